// Round 11
// baseline (186.216 us; speedup 1.0000x reference)
//
#include <hip/hip_runtime.h>
#include <hip/hip_bf16.h>
#include <stdint.h>

#define Bn 8
#define Cn 256
#define Hn 56
#define Wn 56
#define HWn 3136
#define NHEADS 8
#define HDIM 32
#define SEQ 392
#define NSTR 8
#define QKV_LD 768
// SCALE * log2(e): K is pre-scaled by this in the qkv-GEMM epilogue so the
// attention softmax can use exp2 with no per-score multiply.
#define KSC (0.17677669529663689f * 1.4426950408889634f)

#if __has_builtin(__builtin_amdgcn_exp2f)
#define EXP2(x) __builtin_amdgcn_exp2f(x)
#else
#define EXP2(x) exp2f(x)
#endif

typedef short short8 __attribute__((ext_vector_type(8)));
typedef float floatx4 __attribute__((ext_vector_type(4)));

__device__ __forceinline__ unsigned short f2bf(float f) {
  union { float f; uint32_t u; } v; v.f = f;
  uint32_t u = v.u;
  u += 0x7fffu + ((u >> 16) & 1u);   // RNE
  return (unsigned short)(u >> 16);
}
__device__ __forceinline__ float bf2f(unsigned short h) {
  union { uint32_t u; float f; } v; v.u = ((uint32_t)h) << 16;
  return v.f;
}
__device__ __forceinline__ uint32_t cvt_pk_bf16(float lo, float hi) {
  uint32_t r;
  asm("v_cvt_pk_bf16_f32 %0, %1, %2" : "=v"(r) : "v"(lo), "v"(hi));
  return r;
}
// async global->LDS, 16B per lane; LDS dest = wave-uniform base + lane*16
__device__ __forceinline__ void gload16(const unsigned short* g, unsigned short* l) {
  __builtin_amdgcn_global_load_lds((const __attribute__((address_space(1))) void*)g,
                                   (__attribute__((address_space(3))) void*)l, 16, 0, 0);
}

// ---------------- convert fp32 -> bf16 (both weight matrices, one launch) ----------------
__global__ __launch_bounds__(256) void k_cvt2(const float* __restrict__ a,
                                              const float* __restrict__ b2,
                                              unsigned short* __restrict__ da,
                                              unsigned short* __restrict__ db) {
  int i = blockIdx.x * 256 + threadIdx.x;   // 65536 float4 slots total
  if (i < 49152) {
    float4 v = ((const float4*)a)[i];
    ushort4 o;
    o.x = f2bf(v.x); o.y = f2bf(v.y); o.z = f2bf(v.z); o.w = f2bf(v.w);
    ((ushort4*)da)[i] = o;
  } else {
    int k = i - 49152;
    float4 v = ((const float4*)b2)[k];
    ushort4 o;
    o.x = f2bf(v.x); o.y = f2bf(v.y); o.z = f2bf(v.z); o.w = f2bf(v.w);
    ((ushort4*)db)[k] = o;
  }
}

// ---------------- x [B][C][HW] f32 -> xt [B][HW][C] bf16 ----------------
__global__ __launch_bounds__(256) void k_trans_x(const float* __restrict__ x,
                                                 unsigned short* __restrict__ xt) {
  __shared__ float tile[32][33];
  int pb = blockIdx.x, cb = blockIdx.y, b = blockIdx.z;
  int t = threadIdx.x;
  int c = t >> 3, p4 = (t & 7) * 4;
  float4 v = *(const float4*)(x + (((size_t)b * Cn + cb * 32 + c) * HWn + pb * 32 + p4));
  tile[c][p4 + 0] = v.x; tile[c][p4 + 1] = v.y; tile[c][p4 + 2] = v.z; tile[c][p4 + 3] = v.w;
  __syncthreads();
  int p = t >> 3, c4 = (t & 7) * 4;
  ushort4 o;
  o.x = f2bf(tile[c4 + 0][p]); o.y = f2bf(tile[c4 + 1][p]);
  o.z = f2bf(tile[c4 + 2][p]); o.w = f2bf(tile[c4 + 3][p]);
  *(ushort4*)(xt + (((size_t)b * HWn + pb * 32 + p) * Cn + cb * 32 + c4)) = o;
}

// ---------------- GEMM: C[M][N] = A[M][K] * Bt[N][K]^T + bias ----------------
// 512 threads (8 waves: 4 wr x 2 wc, acc 2x4/wave) -> 16 waves/CU at 2 blocks/CU.
// 2-phase double-buffered global_load_lds staging (pre-swizzled source slot^row),
// n-major tile order + XCD batch chunking, LDS-transposed epilogue with
// NONTEMPORAL stores (no L2 write-allocate pollution of the B panel).
// EPI 0: bf16 pixel-major out [N][M] (K-channel rows scaled by KSC); EPI 1: f32 [M][N]
template <int EPI>
__global__ __launch_bounds__(512) void k_gemm(const unsigned short* __restrict__ A,
                                              const unsigned short* __restrict__ Bt,
                                              const float* __restrict__ bias,
                                              unsigned short* __restrict__ outB,
                                              float* __restrict__ outF,
                                              int M, int N, int K, int nm, int nper) {
  __shared__ __align__(16) char SH[EPI ? 67584 : 65536];
  unsigned short* As = (unsigned short*)SH;   // [2][8192]
  unsigned short* Bs = As + 16384;            // [2][8192]
  int t = threadIdx.x;
  int raw = blockIdx.x;
  int chunk = gridDim.x >> 3;
  int wg = (raw & 7) * chunk + (raw >> 3);     // bijective (grid % 8 == 0)
  int b = wg / nper, r = wg % nper;
  int m0 = (r % nm) * 128, n0 = (r / nm) * 128;
  const unsigned short* Bb = Bt + (size_t)b * N * K;
  int lane = t & 63, w = t >> 6;
  int wr = w >> 1, wc = w & 1;
  int g = lane >> 4, q = lane & 15;
  int srow8 = lane >> 3;   // 0..7
  int slot = lane & 7;

  // staging source pointers (k0 added per tile); round i covers rows i*64 + w*8 + srow8
  const unsigned short* Ag[2];
  const unsigned short* Bg[2];
  bool bok[2];
  int ldst[2];
#pragma unroll
  for (int i = 0; i < 2; i++) {
    int row = i * 64 + w * 8 + srow8;
    int cs = slot ^ srow8;                    // row & 7 == srow8
    Ag[i] = A + (size_t)(m0 + row) * K + cs * 8;
    int nr = n0 + row;
    bok[i] = (nr < N);
    Bg[i] = Bb + (size_t)(bok[i] ? nr : (N - 1)) * K + cs * 8;
    ldst[i] = (i * 64 + w * 8) * 64;
  }

  floatx4 z4 = {0.f, 0.f, 0.f, 0.f};
  floatx4 acc[2][4];
#pragma unroll
  for (int i = 0; i < 2; i++)
#pragma unroll
    for (int j = 0; j < 4; j++) acc[i][j] = z4;

  // prologue: stage tile 0
#pragma unroll
  for (int i = 0; i < 2; i++) gload16(Ag[i], &As[ldst[i]]);
#pragma unroll
  for (int i = 0; i < 2; i++) if (bok[i]) gload16(Bg[i], &Bs[ldst[i]]);
  asm volatile("s_waitcnt vmcnt(0)" ::: "memory");
  __syncthreads();

  int cur = 0;
  for (int tt = 0; tt < 4; tt++) {
    if (tt < 3) {   // stage next tile into the other buffer
      int k0 = (tt + 1) * 64;
      int nb = (cur ^ 1) * 8192;
#pragma unroll
      for (int i = 0; i < 2; i++) gload16(Ag[i] + k0, &As[nb + ldst[i]]);
#pragma unroll
      for (int i = 0; i < 2; i++) if (bok[i]) gload16(Bg[i] + k0, &Bs[nb + ldst[i]]);
    }
    int cb = cur * 8192;
#pragma unroll
    for (int kk = 0; kk < 64; kk += 32) {
      short8 af[2], bfr[4];
#pragma unroll
      for (int i = 0; i < 2; i++) {
        int row = wr * 32 + i * 16 + q;
        af[i] = *(const short8*)&As[cb + row * 64 + ((((kk >> 3) + g) ^ (q & 7)) << 3)];
      }
#pragma unroll
      for (int j = 0; j < 4; j++) {
        int row = wc * 64 + j * 16 + q;
        bfr[j] = *(const short8*)&Bs[cb + row * 64 + ((((kk >> 3) + g) ^ (q & 7)) << 3)];
      }
#pragma unroll
      for (int i = 0; i < 2; i++)
#pragma unroll
        for (int j = 0; j < 4; j++)
          acc[i][j] = __builtin_amdgcn_mfma_f32_16x16x32_bf16(af[i], bfr[j], acc[i][j], 0, 0, 0);
    }
    if (tt < 3) {
      asm volatile("s_waitcnt vmcnt(0)" ::: "memory");
      __syncthreads();
      cur ^= 1;
    }
  }

  // ---- LDS-transposed epilogue (dense, coalesced nontemporal global writes) ----
  __syncthreads();   // all waves done reading As/Bs
  if (EPI == 0) {
    unsigned short* E = (unsigned short*)SH;   // [col 128][16 granules x 8ch], XOR-swizzled
#pragma unroll
    for (int i = 0; i < 2; i++) {
      int ob = m0 + wr * 32 + i * 16 + g * 4;
      float bs0 = bias[ob + 0], bs1 = bias[ob + 1], bs2 = bias[ob + 2], bs3 = bias[ob + 3];
      float sc = (ob >= 256 && ob < 512) ? KSC : 1.0f;
      int lobg = wr * 4 + i * 2 + (g >> 1);
#pragma unroll
      for (int j = 0; j < 4; j++) {
        int lc = wc * 64 + j * 16 + q;
        ushort4 o;
        o.x = f2bf((acc[i][j][0] + bs0) * sc);
        o.y = f2bf((acc[i][j][1] + bs1) * sc);
        o.z = f2bf((acc[i][j][2] + bs2) * sc);
        o.w = f2bf((acc[i][j][3] + bs3) * sc);
        *(ushort4*)&E[lc * 128 + ((lobg ^ (lc & 7)) << 3) + (g & 1) * 4] = o;
      }
    }
    __syncthreads();
    int c = t >> 2, part = t & 3;
    int col = n0 + c;
    if (col < N) {
      unsigned short* dst = outB + ((size_t)b * N + col) * M + m0;
#pragma unroll
      for (int k2 = part * 4; k2 < part * 4 + 4; k2++) {   // 4 granules/thread -> all 16
        short8 v = *(const short8*)&E[c * 128 + ((k2 ^ (c & 7)) << 3)];
        __builtin_nontemporal_store(v, (short8*)(dst + k2 * 8));
      }
    }
  } else {
    float* Ef = (float*)SH;   // [row 128][132]
#pragma unroll
    for (int i = 0; i < 2; i++) {
      int ob = m0 + wr * 32 + i * 16 + g * 4;
      int lob = wr * 32 + i * 16 + g * 4;
      float bs0 = bias[ob + 0], bs1 = bias[ob + 1], bs2 = bias[ob + 2], bs3 = bias[ob + 3];
#pragma unroll
      for (int j = 0; j < 4; j++) {
        int lc = wc * 64 + j * 16 + q;
        Ef[(lob + 0) * 132 + lc] = acc[i][j][0] + bs0;
        Ef[(lob + 1) * 132 + lc] = acc[i][j][1] + bs1;
        Ef[(lob + 2) * 132 + lc] = acc[i][j][2] + bs2;
        Ef[(lob + 3) * 132 + lc] = acc[i][j][3] + bs3;
      }
    }
    __syncthreads();
    int rr = t >> 2, seg = t & 3;
    float* dst = outF + (size_t)b * M * N + (size_t)(m0 + rr) * N + n0;
#pragma unroll
    for (int k2 = 0; k2 < 8; k2++) {
      int col = seg * 32 + k2 * 4;
      if (n0 + col < N) {
        floatx4 v = *(const floatx4*)&Ef[rr * 132 + col];
        __builtin_nontemporal_store(v, (floatx4*)(dst + col));
      }
    }
  }
}

// ---------------- depthwise 3x3 on v, output TRANSPOSED: vmt[b][ch][pixel] ----------------
// pass 0: heads 0..3, pixels in h-major order; pass 1: heads 4..7, pixels in
// w-major order. Pass 1 additionally copies q/k channels of heads 4-7 into
// qkvw[b][pixel_w][256] (contiguous 512B writes per pixel).
__global__ __launch_bounds__(256) void k_dwconv_t(const unsigned short* __restrict__ qkv,
                                                  const float* __restrict__ wdw,
                                                  const float* __restrict__ bdw,
                                                  unsigned short* __restrict__ vmt,
                                                  unsigned short* __restrict__ qkvw) {
  __shared__ float wS[1152];
  __shared__ float bS[128];
  __shared__ __align__(16) unsigned short tile[16][140];
  int t = threadIdx.x;
  int pass = blockIdx.y, b = blockIdx.z;
  for (int i = t; i < 1152; i += 256) wS[i] = wdw[pass * 1152 + i];
  if (t < 128) bS[t] = bdw[pass * 128 + t];

  int pi = t >> 4, c8 = (t & 15) * 8;
  int i16 = blockIdx.x * 16 + pi;
  int h, w;
  if (pass == 0) { h = i16 / Wn; w = i16 % Wn; }
  else           { w = i16 / Hn; h = i16 % Hn; }

  // pass 1: w-major q/k side-copy (pixels of this block, full 256 qkvw chans)
  if (pass == 1) {
    int pi2 = t >> 4, c16 = (t & 15) * 16;
    int ib = blockIdx.x * 16 + pi2;
    int w2 = ib / Hn, h2 = ib % Hn;
    size_t src = ((size_t)b * HWn + h2 * Wn + w2) * QKV_LD;
    int sch = (c16 < 128) ? (128 + c16) : (256 + c16);   // q: 128+, k: 384+
    short8 v0 = *(const short8*)(qkv + src + sch);
    short8 v1 = *(const short8*)(qkv + src + sch + 8);
    unsigned short* dst = qkvw + ((size_t)b * HWn + ib) * 256 + c16;
    *(short8*)dst = v0;
    *(short8*)(dst + 8) = v1;
  }
  __syncthreads();

  const unsigned short* vq = qkv + 512 + pass * 128 + c8;
  float a[8];
  short8 vc = *(const short8*)(vq + ((size_t)b * HWn + h * Wn + w) * QKV_LD);
#pragma unroll
  for (int e = 0; e < 8; e++) a[e] = bf2f((unsigned short)vc[e]) + bS[c8 + e];
#pragma unroll
  for (int ky = 0; ky < 3; ky++) {
    int hh = h + ky - 1;
    if (hh < 0 || hh >= Hn) continue;
#pragma unroll
    for (int kx = 0; kx < 3; kx++) {
      int ww = w + kx - 1;
      if (ww < 0 || ww >= Wn) continue;
      short8 vn = *(const short8*)(vq + ((size_t)b * HWn + hh * Wn + ww) * QKV_LD);
#pragma unroll
      for (int e = 0; e < 8; e++) a[e] += bf2f((unsigned short)vn[e]) * wS[(c8 + e) * 9 + ky * 3 + kx];
    }
  }
  short8 o;
#pragma unroll
  for (int e = 0; e < 8; e++) o[e] = (short)f2bf(a[e]);
  *(short8*)&tile[pi][c8] = o;
  __syncthreads();

  int dd = t >> 1, half = t & 1;
  short8 ov;
#pragma unroll
  for (int k2 = 0; k2 < 8; k2++) ov[k2] = (short)tile[half * 8 + k2][dd];
  *(short8*)(vmt + ((size_t)(b * Cn + pass * 128 + dd)) * HWn + blockIdx.x * 16 + half * 8) = ov;
}

// ---------------- stripe attention ----------------
// grid: (stripe 0..7, b*8+hd 0..63), 512 threads (8 waves, one block per stripe)
// h-heads read qkvb (h-major); w-heads read qkvw (w-major) -> both contiguous.
__global__ __launch_bounds__(512) void k_attn(const unsigned short* __restrict__ qkv,
                                              const unsigned short* __restrict__ qkvw,
                                              const unsigned short* __restrict__ vmt,
                                              unsigned short* __restrict__ aout) {
  __shared__ __align__(16) unsigned short Ks[12288];  // 24 j * 4 g * 16 q granules
  __shared__ __align__(16) unsigned short Vf[12800];  // 50 Gc * 32 d granules (d swizzled)
  __shared__ __align__(16) unsigned short Pf[4096];   // 8 waves * 4 Gl * 16 q granules
  int s = blockIdx.x;
  int hd = blockIdx.y & 7, b = blockIdx.y >> 3;
  int t = threadIdx.x, lane = t & 63, wv = t >> 6;
  bool wst = (hd >= 4);
  int q = lane & 15, g = lane >> 4;
  int sbase = s * SEQ;

  const unsigned short* base; int ld, qoff, koff;
  if (wst) { base = qkvw + (size_t)b * HWn * 256;    ld = 256;    qoff = (hd - 4) * 32; koff = 128 + (hd - 4) * 32; }
  else     { base = qkv  + (size_t)b * HWn * QKV_LD; ld = QKV_LD; qoff = hd * 32;       koff = 256 + hd * 32; }

  // ---- Q prefetch: all per-wave Q fragments, issued first ----
  short8 qpre[4];
#pragma unroll
  for (int it = 0; it < 4; it++) {
    int qb = it * 8 + wv;
    int qi = qb * 16 + q;
    int qil = (qi < SEQ) ? qi : 391;
    qpre[it] = *(const short8*)(base + qoff + (size_t)(sbase + qil) * ld + g * 8);
  }

  // ---- stage K keys 0..383, fragment-major ----
  const unsigned short* kgp = base + koff;
#pragma unroll
  for (int P = 0; P < 3; P++) {
    int key = P * 128 + (t >> 2);
    int gg = t & 3;
    short8 kv = *(const short8*)(kgp + (size_t)(sbase + key) * ld + gg * 8);
    *(short8*)&Ks[((((key >> 4) * 4 + gg) * 16) + (key & 15)) * 8] = kv;
  }
  // ---- j=24 K fragment (keys 384..391; 392+ masked later) in regs ----
  short8 kf24;
  {
    int key = 384 + q; if (key > 391) key = 391;
    kf24 = *(const short8*)(kgp + (size_t)(sbase + key) * ld + g * 8);
  }
  // ---- stage V fragment-major with d-swizzle ----
  const unsigned short* vg = vmt + ((size_t)(b * Cn + hd * HDIM)) * HWn + sbase;
  for (int idx = t; idx < 1600; idx += 512) {
    int d = idx / 50, Gc = idx % 50;
    short8 vv = *(const short8*)(vg + (size_t)d * HWn + Gc * 8);
    *(short8*)&Vf[(Gc * 32 + (d ^ (Gc & 7))) * 8] = vv;
  }
  __syncthreads();

  floatx4 z4 = {0.f, 0.f, 0.f, 0.f};
  unsigned short* Pw = &Pf[wv * 512];
  int gh = g >> 1, ge = (g & 1) * 4;

#pragma unroll
  for (int it = 0; it < 4; it++) {
    int qb = it * 8 + wv;
    if (qb >= 25) continue;
    int qi = qb * 16 + q;
    int qil = (qi < SEQ) ? qi : 391;
    short8 qf = qpre[it];

    // QK^T (swapped): lane holds S^T[key 4g+r][query q], in log2 units
    floatx4 sacc[25];
#pragma unroll
    for (int j = 0; j < 24; j++) {
      short8 kf = *(const short8*)&Ks[((j * 4 + g) * 16 + q) * 8];
      sacc[j] = __builtin_amdgcn_mfma_f32_16x16x32_bf16(kf, qf, z4, 0, 0, 0);
    }
    sacc[24] = __builtin_amdgcn_mfma_f32_16x16x32_bf16(kf24, qf, z4, 0, 0, 0);
    if (g >= 2) { sacc[24][0] = sacc[24][1] = sacc[24][2] = sacc[24][3] = -3.0e38f; }

    // softmax sans max-subtraction (scores bounded; masked -> exp2 -> 0)
    float sm = 0.f;
#pragma unroll
    for (int j = 0; j < 25; j++) {
      float e0 = EXP2(sacc[j][0]); float e1 = EXP2(sacc[j][1]);
      float e2 = EXP2(sacc[j][2]); float e3 = EXP2(sacc[j][3]);
      sacc[j][0] = e0; sacc[j][1] = e1; sacc[j][2] = e2; sacc[j][3] = e3;
      sm += (e0 + e1) + (e2 + e3);
    }
    sm += __shfl_xor(sm, 16);
    sm += __shfl_xor(sm, 32);
    float rcp = 1.0f / sm;

// jbW is clamped to stay in-bounds textually; the guard keeps semantics.
#define WRITEP(cc) do {                                                        \
    enum { jbW = (2*(cc)+1 < 25) ? (2*(cc)+1) : 24 };                          \
    uint2 wA, wB;                                                              \
    wA.x = cvt_pk_bf16(sacc[2*(cc)][0], sacc[2*(cc)][1]);                      \
    wA.y = cvt_pk_bf16(sacc[2*(cc)][2], sacc[2*(cc)][3]);                      \
    if (2*(cc)+1 < 25) {                                                       \
      wB.x = cvt_pk_bf16(sacc[jbW][0], sacc[jbW][1]);                          \
      wB.y = cvt_pk_bf16(sacc[jbW][2], sacc[jbW][3]);                          \
    } else { wB.x = 0u; wB.y = 0u; }                                           \
    *(uint2*)&Pw[(gh * 16 + q) * 8 + ge] = wA;                                 \
    *(uint2*)&Pw[((2 + gh) * 16 + q) * 8 + ge] = wB;                           \
  } while (0)

    // PV: 13 chunks of 32 keys; P round-trips per-wave LDS, pipelined 1 ahead
    floatx4 o0 = z4, o1 = z4;
    WRITEP(0);
#pragma unroll
    for (int ch = 0; ch < 13; ch++) {
      asm volatile("s_waitcnt lgkmcnt(0)" ::: "memory");
      short8 pfr = *(const short8*)&Pw[(g * 16 + q) * 8];
      int Gc = ch * 4 + g; if (Gc > 49) Gc = 49;
      int sw = Gc & 7;
      short8 vf0 = *(const short8*)&Vf[(Gc * 32 + (q ^ sw)) * 8];
      short8 vf1 = *(const short8*)&Vf[(Gc * 32 + 16 + (q ^ sw)) * 8];
      if (ch < 12) {
        switch (ch + 1) {   // keep sacc indices compile-time after unroll
          case 1: WRITEP(1); break;  case 2: WRITEP(2); break;
          case 3: WRITEP(3); break;  case 4: WRITEP(4); break;
          case 5: WRITEP(5); break;  case 6: WRITEP(6); break;
          case 7: WRITEP(7); break;  case 8: WRITEP(8); break;
          case 9: WRITEP(9); break;  case 10: WRITEP(10); break;
          case 11: WRITEP(11); break; case 12: WRITEP(12); break;
        }
      }
      o0 = __builtin_amdgcn_mfma_f32_16x16x32_bf16(vf0, pfr, o0, 0, 0, 0);
      o1 = __builtin_amdgcn_mfma_f32_16x16x32_bf16(vf1, pfr, o1, 0, 0, 0);
    }
#undef WRITEP

    if (qi < SEQ) {
      int pq = wst ? ((qil % Wn) * Wn + s * 7 + qil / Wn) : (sbase + qil);
      size_t ob = ((size_t)b * HWn + pq) * Cn + hd * HDIM;
      ushort4 u0, u1;
      u0.x = f2bf(o0[0] * rcp); u0.y = f2bf(o0[1] * rcp);
      u0.z = f2bf(o0[2] * rcp); u0.w = f2bf(o0[3] * rcp);
      u1.x = f2bf(o1[0] * rcp); u1.y = f2bf(o1[1] * rcp);
      u1.z = f2bf(o1[2] * rcp); u1.w = f2bf(o1[3] * rcp);
      *(ushort4*)(aout + ob + g * 4) = u0;
      *(ushort4*)(aout + ob + 16 + g * 4) = u1;
    }
  }
}

extern "C" void kernel_launch(void* const* d_in, const int* in_sizes, int n_in,
                              void* d_out, int out_size, void* d_ws, size_t ws_size,
                              hipStream_t stream) {
  const float* x     = (const float*)d_in[0];
  const float* wqkv  = (const float*)d_in[1];
  const float* bqkv  = (const float*)d_in[2];
  const float* wdw   = (const float*)d_in[3];
  const float* bdw   = (const float*)d_in[4];
  const float* wproj = (const float*)d_in[5];
  const float* bproj = (const float*)d_in[6];
  float* out = (float*)d_out;

  unsigned short* xt   = (unsigned short*)d_ws;                    // [B][HW][256] bf16
  unsigned short* wqb  = xt + (size_t)Bn * HWn * Cn;               // [768][256]
  unsigned short* wpb  = wqb + 768 * 256;                          // [256][256]
  unsigned short* qkvb = wpb + 256 * 256;                          // [B][HW][768] bf16
  unsigned short* vmt  = qkvb + (size_t)Bn * HWn * QKV_LD;         // [B][256ch][HW] bf16
  unsigned short* aout = vmt + (size_t)Bn * HWn * Cn;              // [B][HW][256] bf16
  unsigned short* qkvw = aout + (size_t)Bn * HWn * Cn;             // [B][HW_wmaj][256] bf16

  k_cvt2<<<dim3(256), 256, 0, stream>>>(wqkv, wproj, wqb, wpb);
  k_trans_x<<<dim3(98, 8, Bn), 256, 0, stream>>>(x, xt);
  k_gemm<0><<<dim3(1200), 512, 0, stream>>>(wqb, xt, bqkv, qkvb, nullptr, 768, HWn, 256, 6, 150);
  k_dwconv_t<<<dim3(196, 2, Bn), 256, 0, stream>>>(qkvb, wdw, bdw, vmt, qkvw);
  k_attn<<<dim3(NSTR, Bn * NHEADS), 512, 0, stream>>>(qkvb, qkvw, vmt, aout);
  k_gemm<1><<<dim3(400), 512, 0, stream>>>(wpb, aout, bproj, nullptr, out, 256, HWn, 256, 2, 50);
}

// Round 12
// 114.106 us; speedup vs baseline: 1.6320x; 1.6320x over previous
//
#include <hip/hip_runtime.h>
#include <hip/hip_bf16.h>
#include <stdint.h>

#define Bn 8
#define Cn 256
#define Hn 56
#define Wn 56
#define HWn 3136
#define NHEADS 8
#define HDIM 32
#define SEQ 392
#define NSTR 8
#define QKV_LD 768
// SCALE * log2(e): K is pre-scaled by this in the qkv-GEMM epilogue so the
// attention softmax can use exp2 with no per-score multiply.
#define KSC (0.17677669529663689f * 1.4426950408889634f)

#if __has_builtin(__builtin_amdgcn_exp2f)
#define EXP2(x) __builtin_amdgcn_exp2f(x)
#else
#define EXP2(x) exp2f(x)
#endif

typedef short short8 __attribute__((ext_vector_type(8)));
typedef float floatx4 __attribute__((ext_vector_type(4)));

__device__ __forceinline__ unsigned short f2bf(float f) {
  union { float f; uint32_t u; } v; v.f = f;
  uint32_t u = v.u;
  u += 0x7fffu + ((u >> 16) & 1u);   // RNE
  return (unsigned short)(u >> 16);
}
__device__ __forceinline__ float bf2f(unsigned short h) {
  union { uint32_t u; float f; } v; v.u = ((uint32_t)h) << 16;
  return v.f;
}
__device__ __forceinline__ uint32_t cvt_pk_bf16(float lo, float hi) {
  uint32_t r;
  asm("v_cvt_pk_bf16_f32 %0, %1, %2" : "=v"(r) : "v"(lo), "v"(hi));
  return r;
}
// async global->LDS, 16B per lane; LDS dest = wave-uniform base + lane*16
__device__ __forceinline__ void gload16(const unsigned short* g, unsigned short* l) {
  __builtin_amdgcn_global_load_lds((const __attribute__((address_space(1))) void*)g,
                                   (__attribute__((address_space(3))) void*)l, 16, 0, 0);
}

// ---------------- convert fp32 -> bf16 (both weight matrices, one launch) ----------------
__global__ __launch_bounds__(256) void k_cvt2(const float* __restrict__ a,
                                              const float* __restrict__ b2,
                                              unsigned short* __restrict__ da,
                                              unsigned short* __restrict__ db) {
  int i = blockIdx.x * 256 + threadIdx.x;   // 65536 float4 slots total
  if (i < 49152) {
    float4 v = ((const float4*)a)[i];
    ushort4 o;
    o.x = f2bf(v.x); o.y = f2bf(v.y); o.z = f2bf(v.z); o.w = f2bf(v.w);
    ((ushort4*)da)[i] = o;
  } else {
    int k = i - 49152;
    float4 v = ((const float4*)b2)[k];
    ushort4 o;
    o.x = f2bf(v.x); o.y = f2bf(v.y); o.z = f2bf(v.z); o.w = f2bf(v.w);
    ((ushort4*)db)[k] = o;
  }
}

// ---------------- x [B][C][HW] f32 -> xt [B][HW][C] bf16 ----------------
__global__ __launch_bounds__(256) void k_trans_x(const float* __restrict__ x,
                                                 unsigned short* __restrict__ xt) {
  __shared__ float tile[32][33];
  int pb = blockIdx.x, cb = blockIdx.y, b = blockIdx.z;
  int t = threadIdx.x;
  int c = t >> 3, p4 = (t & 7) * 4;
  float4 v = *(const float4*)(x + (((size_t)b * Cn + cb * 32 + c) * HWn + pb * 32 + p4));
  tile[c][p4 + 0] = v.x; tile[c][p4 + 1] = v.y; tile[c][p4 + 2] = v.z; tile[c][p4 + 3] = v.w;
  __syncthreads();
  int p = t >> 3, c4 = (t & 7) * 4;
  ushort4 o;
  o.x = f2bf(tile[c4 + 0][p]); o.y = f2bf(tile[c4 + 1][p]);
  o.z = f2bf(tile[c4 + 2][p]); o.w = f2bf(tile[c4 + 3][p]);
  *(ushort4*)(xt + (((size_t)b * HWn + pb * 32 + p) * Cn + cb * 32 + c4)) = o;
}

// ---------------- GEMM: C[M][N] = A[M][K] * Bt[N][K]^T + bias ----------------
// 512 threads (8 waves: 4 wr x 2 wc, acc 2x4/wave) -> 16 waves/CU at 2 blocks/CU.
// 2-phase double-buffered global_load_lds staging (pre-swizzled source slot^row),
// n-major tile order + XCD batch chunking (FETCH 40->7 MB, R11-verified),
// LDS-transposed epilogue -> dense coalesced stores (plain, NOT nontemporal:
// NT 16B stores caused 4x DRAM write amplification, R11).
// EPI 0: bf16 pixel-major out [N][M] (K-channel rows scaled by KSC); EPI 1: f32 [M][N]
template <int EPI>
__global__ __launch_bounds__(512) void k_gemm(const unsigned short* __restrict__ A,
                                              const unsigned short* __restrict__ Bt,
                                              const float* __restrict__ bias,
                                              unsigned short* __restrict__ outB,
                                              float* __restrict__ outF,
                                              int M, int N, int K, int nm, int nper) {
  __shared__ __align__(16) char SH[EPI ? 67584 : 65536];
  unsigned short* As = (unsigned short*)SH;   // [2][8192]
  unsigned short* Bs = As + 16384;            // [2][8192]
  int t = threadIdx.x;
  int raw = blockIdx.x;
  int chunk = gridDim.x >> 3;
  int wg = (raw & 7) * chunk + (raw >> 3);     // bijective (grid % 8 == 0)
  int b = wg / nper, r = wg % nper;
  int m0 = (r % nm) * 128, n0 = (r / nm) * 128;
  const unsigned short* Bb = Bt + (size_t)b * N * K;
  int lane = t & 63, w = t >> 6;
  int wr = w >> 1, wc = w & 1;
  int g = lane >> 4, q = lane & 15;
  int srow8 = lane >> 3;   // 0..7
  int slot = lane & 7;

  // staging source pointers (k0 added per tile); round i covers rows i*64 + w*8 + srow8
  const unsigned short* Ag[2];
  const unsigned short* Bg[2];
  bool bok[2];
  int ldst[2];
#pragma unroll
  for (int i = 0; i < 2; i++) {
    int row = i * 64 + w * 8 + srow8;
    int cs = slot ^ srow8;                    // row & 7 == srow8
    Ag[i] = A + (size_t)(m0 + row) * K + cs * 8;
    int nr = n0 + row;
    bok[i] = (nr < N);
    Bg[i] = Bb + (size_t)(bok[i] ? nr : (N - 1)) * K + cs * 8;
    ldst[i] = (i * 64 + w * 8) * 64;
  }

  floatx4 z4 = {0.f, 0.f, 0.f, 0.f};
  floatx4 acc[2][4];
#pragma unroll
  for (int i = 0; i < 2; i++)
#pragma unroll
    for (int j = 0; j < 4; j++) acc[i][j] = z4;

  // prologue: stage tile 0
#pragma unroll
  for (int i = 0; i < 2; i++) gload16(Ag[i], &As[ldst[i]]);
#pragma unroll
  for (int i = 0; i < 2; i++) if (bok[i]) gload16(Bg[i], &Bs[ldst[i]]);
  asm volatile("s_waitcnt vmcnt(0)" ::: "memory");
  __syncthreads();

  int cur = 0;
  for (int tt = 0; tt < 4; tt++) {
    if (tt < 3) {   // stage next tile into the other buffer
      int k0 = (tt + 1) * 64;
      int nb = (cur ^ 1) * 8192;
#pragma unroll
      for (int i = 0; i < 2; i++) gload16(Ag[i] + k0, &As[nb + ldst[i]]);
#pragma unroll
      for (int i = 0; i < 2; i++) if (bok[i]) gload16(Bg[i] + k0, &Bs[nb + ldst[i]]);
    }
    int cb = cur * 8192;
#pragma unroll
    for (int kk = 0; kk < 64; kk += 32) {
      short8 af[2], bfr[4];
#pragma unroll
      for (int i = 0; i < 2; i++) {
        int row = wr * 32 + i * 16 + q;
        af[i] = *(const short8*)&As[cb + row * 64 + ((((kk >> 3) + g) ^ (q & 7)) << 3)];
      }
#pragma unroll
      for (int j = 0; j < 4; j++) {
        int row = wc * 64 + j * 16 + q;
        bfr[j] = *(const short8*)&Bs[cb + row * 64 + ((((kk >> 3) + g) ^ (q & 7)) << 3)];
      }
#pragma unroll
      for (int i = 0; i < 2; i++)
#pragma unroll
        for (int j = 0; j < 4; j++)
          acc[i][j] = __builtin_amdgcn_mfma_f32_16x16x32_bf16(af[i], bfr[j], acc[i][j], 0, 0, 0);
    }
    if (tt < 3) {
      asm volatile("s_waitcnt vmcnt(0)" ::: "memory");
      __syncthreads();
      cur ^= 1;
    }
  }

  // ---- LDS-transposed epilogue (dense, coalesced global writes) ----
  __syncthreads();   // all waves done reading As/Bs
  if (EPI == 0) {
    unsigned short* E = (unsigned short*)SH;   // [col 128][16 granules x 8ch], XOR-swizzled
#pragma unroll
    for (int i = 0; i < 2; i++) {
      int ob = m0 + wr * 32 + i * 16 + g * 4;
      float bs0 = bias[ob + 0], bs1 = bias[ob + 1], bs2 = bias[ob + 2], bs3 = bias[ob + 3];
      float sc = (ob >= 256 && ob < 512) ? KSC : 1.0f;
      int lobg = wr * 4 + i * 2 + (g >> 1);
#pragma unroll
      for (int j = 0; j < 4; j++) {
        int lc = wc * 64 + j * 16 + q;
        ushort4 o;
        o.x = f2bf((acc[i][j][0] + bs0) * sc);
        o.y = f2bf((acc[i][j][1] + bs1) * sc);
        o.z = f2bf((acc[i][j][2] + bs2) * sc);
        o.w = f2bf((acc[i][j][3] + bs3) * sc);
        *(ushort4*)&E[lc * 128 + ((lobg ^ (lc & 7)) << 3) + (g & 1) * 4] = o;
      }
    }
    __syncthreads();
    int c = t >> 2, part = t & 3;
    int col = n0 + c;
    if (col < N) {
      unsigned short* dst = outB + ((size_t)b * N + col) * M + m0;
#pragma unroll
      for (int k2 = part * 4; k2 < part * 4 + 4; k2++) {   // 4 granules/thread -> all 16
        short8 v = *(const short8*)&E[c * 128 + ((k2 ^ (c & 7)) << 3)];
        *(short8*)(dst + k2 * 8) = v;
      }
    }
  } else {
    float* Ef = (float*)SH;   // [row 128][132]
#pragma unroll
    for (int i = 0; i < 2; i++) {
      int ob = m0 + wr * 32 + i * 16 + g * 4;
      int lob = wr * 32 + i * 16 + g * 4;
      float bs0 = bias[ob + 0], bs1 = bias[ob + 1], bs2 = bias[ob + 2], bs3 = bias[ob + 3];
#pragma unroll
      for (int j = 0; j < 4; j++) {
        int lc = wc * 64 + j * 16 + q;
        Ef[(lob + 0) * 132 + lc] = acc[i][j][0] + bs0;
        Ef[(lob + 1) * 132 + lc] = acc[i][j][1] + bs1;
        Ef[(lob + 2) * 132 + lc] = acc[i][j][2] + bs2;
        Ef[(lob + 3) * 132 + lc] = acc[i][j][3] + bs3;
      }
    }
    __syncthreads();
    int rr = t >> 2, seg = t & 3;
    float* dst = outF + (size_t)b * M * N + (size_t)(m0 + rr) * N + n0;
#pragma unroll
    for (int k2 = 0; k2 < 8; k2++) {
      int col = seg * 32 + k2 * 4;
      if (n0 + col < N) {
        floatx4 v = *(const floatx4*)&Ef[rr * 132 + col];
        *(floatx4*)(dst + col) = v;
      }
    }
  }
}

// ---------------- depthwise 3x3 on v, output TRANSPOSED: vmt[b][ch][pixel] ----------------
// pass 0: heads 0..3, pixels in h-major order; pass 1: heads 4..7, pixels in
// w-major order. Pass 1 additionally copies q/k channels of heads 4-7 into
// qkvw[b][pixel_w][256] (contiguous 512B writes per pixel).
__global__ __launch_bounds__(256) void k_dwconv_t(const unsigned short* __restrict__ qkv,
                                                  const float* __restrict__ wdw,
                                                  const float* __restrict__ bdw,
                                                  unsigned short* __restrict__ vmt,
                                                  unsigned short* __restrict__ qkvw) {
  __shared__ float wS[1152];
  __shared__ float bS[128];
  __shared__ __align__(16) unsigned short tile[16][140];
  int t = threadIdx.x;
  int pass = blockIdx.y, b = blockIdx.z;
  for (int i = t; i < 1152; i += 256) wS[i] = wdw[pass * 1152 + i];
  if (t < 128) bS[t] = bdw[pass * 128 + t];

  int pi = t >> 4, c8 = (t & 15) * 8;
  int i16 = blockIdx.x * 16 + pi;
  int h, w;
  if (pass == 0) { h = i16 / Wn; w = i16 % Wn; }
  else           { w = i16 / Hn; h = i16 % Hn; }

  // pass 1: w-major q/k side-copy (pixels of this block, full 256 qkvw chans)
  if (pass == 1) {
    int pi2 = t >> 4, c16 = (t & 15) * 16;
    int ib = blockIdx.x * 16 + pi2;
    int w2 = ib / Hn, h2 = ib % Hn;
    size_t src = ((size_t)b * HWn + h2 * Wn + w2) * QKV_LD;
    int sch = (c16 < 128) ? (128 + c16) : (256 + c16);   // q: 128+, k: 384+
    short8 v0 = *(const short8*)(qkv + src + sch);
    short8 v1 = *(const short8*)(qkv + src + sch + 8);
    unsigned short* dst = qkvw + ((size_t)b * HWn + ib) * 256 + c16;
    *(short8*)dst = v0;
    *(short8*)(dst + 8) = v1;
  }
  __syncthreads();

  const unsigned short* vq = qkv + 512 + pass * 128 + c8;
  float a[8];
  short8 vc = *(const short8*)(vq + ((size_t)b * HWn + h * Wn + w) * QKV_LD);
#pragma unroll
  for (int e = 0; e < 8; e++) a[e] = bf2f((unsigned short)vc[e]) + bS[c8 + e];
#pragma unroll
  for (int ky = 0; ky < 3; ky++) {
    int hh = h + ky - 1;
    if (hh < 0 || hh >= Hn) continue;
#pragma unroll
    for (int kx = 0; kx < 3; kx++) {
      int ww = w + kx - 1;
      if (ww < 0 || ww >= Wn) continue;
      short8 vn = *(const short8*)(vq + ((size_t)b * HWn + hh * Wn + ww) * QKV_LD);
#pragma unroll
      for (int e = 0; e < 8; e++) a[e] += bf2f((unsigned short)vn[e]) * wS[(c8 + e) * 9 + ky * 3 + kx];
    }
  }
  short8 o;
#pragma unroll
  for (int e = 0; e < 8; e++) o[e] = (short)f2bf(a[e]);
  *(short8*)&tile[pi][c8] = o;
  __syncthreads();

  int dd = t >> 1, half = t & 1;
  short8 ov;
#pragma unroll
  for (int k2 = 0; k2 < 8; k2++) ov[k2] = (short)tile[half * 8 + k2][dd];
  *(short8*)(vmt + ((size_t)(b * Cn + pass * 128 + dd)) * HWn + blockIdx.x * 16 + half * 8) = ov;
}

// ---------------- stripe attention ----------------
// grid: (stripe 0..7, b*8+hd 0..63), 512 threads (8 waves, one block per stripe)
// h-heads read qkvb (h-major); w-heads read qkvw (w-major) -> both contiguous.
__global__ __launch_bounds__(512) void k_attn(const unsigned short* __restrict__ qkv,
                                              const unsigned short* __restrict__ qkvw,
                                              const unsigned short* __restrict__ vmt,
                                              unsigned short* __restrict__ aout) {
  __shared__ __align__(16) unsigned short Ks[12288];  // 24 j * 4 g * 16 q granules
  __shared__ __align__(16) unsigned short Vf[12800];  // 50 Gc * 32 d granules (d swizzled)
  __shared__ __align__(16) unsigned short Pf[4096];   // 8 waves * 4 Gl * 16 q granules
  int s = blockIdx.x;
  int hd = blockIdx.y & 7, b = blockIdx.y >> 3;
  int t = threadIdx.x, lane = t & 63, wv = t >> 6;
  bool wst = (hd >= 4);
  int q = lane & 15, g = lane >> 4;
  int sbase = s * SEQ;

  const unsigned short* base; int ld, qoff, koff;
  if (wst) { base = qkvw + (size_t)b * HWn * 256;    ld = 256;    qoff = (hd - 4) * 32; koff = 128 + (hd - 4) * 32; }
  else     { base = qkv  + (size_t)b * HWn * QKV_LD; ld = QKV_LD; qoff = hd * 32;       koff = 256 + hd * 32; }

  // ---- Q prefetch: all per-wave Q fragments, issued first ----
  short8 qpre[4];
#pragma unroll
  for (int it = 0; it < 4; it++) {
    int qb = it * 8 + wv;
    int qi = qb * 16 + q;
    int qil = (qi < SEQ) ? qi : 391;
    qpre[it] = *(const short8*)(base + qoff + (size_t)(sbase + qil) * ld + g * 8);
  }

  // ---- stage K keys 0..383, fragment-major ----
  const unsigned short* kgp = base + koff;
#pragma unroll
  for (int P = 0; P < 3; P++) {
    int key = P * 128 + (t >> 2);
    int gg = t & 3;
    short8 kv = *(const short8*)(kgp + (size_t)(sbase + key) * ld + gg * 8);
    *(short8*)&Ks[((((key >> 4) * 4 + gg) * 16) + (key & 15)) * 8] = kv;
  }
  // ---- j=24 K fragment (keys 384..391; 392+ masked later) in regs ----
  short8 kf24;
  {
    int key = 384 + q; if (key > 391) key = 391;
    kf24 = *(const short8*)(kgp + (size_t)(sbase + key) * ld + g * 8);
  }
  // ---- stage V fragment-major with d-swizzle ----
  const unsigned short* vg = vmt + ((size_t)(b * Cn + hd * HDIM)) * HWn + sbase;
  for (int idx = t; idx < 1600; idx += 512) {
    int d = idx / 50, Gc = idx % 50;
    short8 vv = *(const short8*)(vg + (size_t)d * HWn + Gc * 8);
    *(short8*)&Vf[(Gc * 32 + (d ^ (Gc & 7))) * 8] = vv;
  }
  __syncthreads();

  floatx4 z4 = {0.f, 0.f, 0.f, 0.f};
  unsigned short* Pw = &Pf[wv * 512];
  int gh = g >> 1, ge = (g & 1) * 4;

#pragma unroll
  for (int it = 0; it < 4; it++) {
    int qb = it * 8 + wv;
    if (qb >= 25) continue;
    int qi = qb * 16 + q;
    int qil = (qi < SEQ) ? qi : 391;
    short8 qf = qpre[it];

    // QK^T (swapped): lane holds S^T[key 4g+r][query q], in log2 units
    floatx4 sacc[25];
#pragma unroll
    for (int j = 0; j < 24; j++) {
      short8 kf = *(const short8*)&Ks[((j * 4 + g) * 16 + q) * 8];
      sacc[j] = __builtin_amdgcn_mfma_f32_16x16x32_bf16(kf, qf, z4, 0, 0, 0);
    }
    sacc[24] = __builtin_amdgcn_mfma_f32_16x16x32_bf16(kf24, qf, z4, 0, 0, 0);
    if (g >= 2) { sacc[24][0] = sacc[24][1] = sacc[24][2] = sacc[24][3] = -3.0e38f; }

    // softmax sans max-subtraction (scores bounded; masked -> exp2 -> 0)
    float sm = 0.f;
#pragma unroll
    for (int j = 0; j < 25; j++) {
      float e0 = EXP2(sacc[j][0]); float e1 = EXP2(sacc[j][1]);
      float e2 = EXP2(sacc[j][2]); float e3 = EXP2(sacc[j][3]);
      sacc[j][0] = e0; sacc[j][1] = e1; sacc[j][2] = e2; sacc[j][3] = e3;
      sm += (e0 + e1) + (e2 + e3);
    }
    sm += __shfl_xor(sm, 16);
    sm += __shfl_xor(sm, 32);
    float rcp = 1.0f / sm;

// jbW is clamped to stay in-bounds textually; the guard keeps semantics.
#define WRITEP(cc) do {                                                        \
    enum { jbW = (2*(cc)+1 < 25) ? (2*(cc)+1) : 24 };                          \
    uint2 wA, wB;                                                              \
    wA.x = cvt_pk_bf16(sacc[2*(cc)][0], sacc[2*(cc)][1]);                      \
    wA.y = cvt_pk_bf16(sacc[2*(cc)][2], sacc[2*(cc)][3]);                      \
    if (2*(cc)+1 < 25) {                                                       \
      wB.x = cvt_pk_bf16(sacc[jbW][0], sacc[jbW][1]);                          \
      wB.y = cvt_pk_bf16(sacc[jbW][2], sacc[jbW][3]);                          \
    } else { wB.x = 0u; wB.y = 0u; }                                           \
    *(uint2*)&Pw[(gh * 16 + q) * 8 + ge] = wA;                                 \
    *(uint2*)&Pw[((2 + gh) * 16 + q) * 8 + ge] = wB;                           \
  } while (0)

    // PV: 13 chunks of 32 keys; P round-trips per-wave LDS, pipelined 1 ahead
    floatx4 o0 = z4, o1 = z4;
    WRITEP(0);
#pragma unroll
    for (int ch = 0; ch < 13; ch++) {
      asm volatile("s_waitcnt lgkmcnt(0)" ::: "memory");
      short8 pfr = *(const short8*)&Pw[(g * 16 + q) * 8];
      int Gc = ch * 4 + g; if (Gc > 49) Gc = 49;
      int sw = Gc & 7;
      short8 vf0 = *(const short8*)&Vf[(Gc * 32 + (q ^ sw)) * 8];
      short8 vf1 = *(const short8*)&Vf[(Gc * 32 + 16 + (q ^ sw)) * 8];
      if (ch < 12) {
        switch (ch + 1) {   // keep sacc indices compile-time after unroll
          case 1: WRITEP(1); break;  case 2: WRITEP(2); break;
          case 3: WRITEP(3); break;  case 4: WRITEP(4); break;
          case 5: WRITEP(5); break;  case 6: WRITEP(6); break;
          case 7: WRITEP(7); break;  case 8: WRITEP(8); break;
          case 9: WRITEP(9); break;  case 10: WRITEP(10); break;
          case 11: WRITEP(11); break; case 12: WRITEP(12); break;
        }
      }
      o0 = __builtin_amdgcn_mfma_f32_16x16x32_bf16(vf0, pfr, o0, 0, 0, 0);
      o1 = __builtin_amdgcn_mfma_f32_16x16x32_bf16(vf1, pfr, o1, 0, 0, 0);
    }
#undef WRITEP

    if (qi < SEQ) {
      int pq = wst ? ((qil % Wn) * Wn + s * 7 + qil / Wn) : (sbase + qil);
      size_t ob = ((size_t)b * HWn + pq) * Cn + hd * HDIM;
      ushort4 u0, u1;
      u0.x = f2bf(o0[0] * rcp); u0.y = f2bf(o0[1] * rcp);
      u0.z = f2bf(o0[2] * rcp); u0.w = f2bf(o0[3] * rcp);
      u1.x = f2bf(o1[0] * rcp); u1.y = f2bf(o1[1] * rcp);
      u1.z = f2bf(o1[2] * rcp); u1.w = f2bf(o1[3] * rcp);
      *(ushort4*)(aout + ob + g * 4) = u0;
      *(ushort4*)(aout + ob + 16 + g * 4) = u1;
    }
  }
}

extern "C" void kernel_launch(void* const* d_in, const int* in_sizes, int n_in,
                              void* d_out, int out_size, void* d_ws, size_t ws_size,
                              hipStream_t stream) {
  const float* x     = (const float*)d_in[0];
  const float* wqkv  = (const float*)d_in[1];
  const float* bqkv  = (const float*)d_in[2];
  const float* wdw   = (const float*)d_in[3];
  const float* bdw   = (const float*)d_in[4];
  const float* wproj = (const float*)d_in[5];
  const float* bproj = (const float*)d_in[6];
  float* out = (float*)d_out;

  unsigned short* xt   = (unsigned short*)d_ws;                    // [B][HW][256] bf16
  unsigned short* wqb  = xt + (size_t)Bn * HWn * Cn;               // [768][256]
  unsigned short* wpb  = wqb + 768 * 256;                          // [256][256]
  unsigned short* qkvb = wpb + 256 * 256;                          // [B][HW][768] bf16
  unsigned short* vmt  = qkvb + (size_t)Bn * HWn * QKV_LD;         // [B][256ch][HW] bf16
  unsigned short* aout = vmt + (size_t)Bn * HWn * Cn;              // [B][HW][256] bf16
  unsigned short* qkvw = aout + (size_t)Bn * HWn * Cn;             // [B][HW_wmaj][256] bf16

  k_cvt2<<<dim3(256), 256, 0, stream>>>(wqkv, wproj, wqb, wpb);
  k_trans_x<<<dim3(98, 8, Bn), 256, 0, stream>>>(x, xt);
  k_gemm<0><<<dim3(1200), 512, 0, stream>>>(wqb, xt, bqkv, qkvb, nullptr, 768, HWn, 256, 6, 150);
  k_dwconv_t<<<dim3(196, 2, Bn), 256, 0, stream>>>(qkvb, wdw, bdw, vmt, qkvw);
  k_attn<<<dim3(NSTR, Bn * NHEADS), 512, 0, stream>>>(qkvb, qkvw, vmt, aout);
  k_gemm<1><<<dim3(400), 512, 0, stream>>>(wpb, aout, bproj, nullptr, out, 256, HWn, 256, 2, 50);
}

// Round 13
// 108.483 us; speedup vs baseline: 1.7165x; 1.0518x over previous
//
#include <hip/hip_runtime.h>
#include <hip/hip_bf16.h>
#include <stdint.h>

#define Bn 8
#define Cn 256
#define Hn 56
#define Wn 56
#define HWn 3136
#define NHEADS 8
#define HDIM 32
#define SEQ 392
#define NSTR 8
#define QKV_LD 768
// SCALE * log2(e): K is pre-scaled by this in the qkv-GEMM epilogue so the
// attention softmax can use exp2 with no per-score multiply.
#define KSC (0.17677669529663689f * 1.4426950408889634f)

#if __has_builtin(__builtin_amdgcn_exp2f)
#define EXP2(x) __builtin_amdgcn_exp2f(x)
#else
#define EXP2(x) exp2f(x)
#endif

typedef short short8 __attribute__((ext_vector_type(8)));
typedef float floatx4 __attribute__((ext_vector_type(4)));

__device__ __forceinline__ unsigned short f2bf(float f) {
  union { float f; uint32_t u; } v; v.f = f;
  uint32_t u = v.u;
  u += 0x7fffu + ((u >> 16) & 1u);   // RNE
  return (unsigned short)(u >> 16);
}
__device__ __forceinline__ float bf2f(unsigned short h) {
  union { uint32_t u; float f; } v; v.u = ((uint32_t)h) << 16;
  return v.f;
}
__device__ __forceinline__ uint32_t cvt_pk_bf16(float lo, float hi) {
  uint32_t r;
  asm("v_cvt_pk_bf16_f32 %0, %1, %2" : "=v"(r) : "v"(lo), "v"(hi));
  return r;
}
// async global->LDS, 16B per lane; LDS dest = wave-uniform base + lane*16
__device__ __forceinline__ void gload16(const unsigned short* g, unsigned short* l) {
  __builtin_amdgcn_global_load_lds((const __attribute__((address_space(1))) void*)g,
                                   (__attribute__((address_space(3))) void*)l, 16, 0, 0);
}

// ---------------- convert fp32 -> bf16 (both weight matrices, one launch) ----------------
__global__ __launch_bounds__(256) void k_cvt2(const float* __restrict__ a,
                                              const float* __restrict__ b2,
                                              unsigned short* __restrict__ da,
                                              unsigned short* __restrict__ db) {
  int i = blockIdx.x * 256 + threadIdx.x;   // 65536 float4 slots total
  if (i < 49152) {
    float4 v = ((const float4*)a)[i];
    ushort4 o;
    o.x = f2bf(v.x); o.y = f2bf(v.y); o.z = f2bf(v.z); o.w = f2bf(v.w);
    ((ushort4*)da)[i] = o;
  } else {
    int k = i - 49152;
    float4 v = ((const float4*)b2)[k];
    ushort4 o;
    o.x = f2bf(v.x); o.y = f2bf(v.y); o.z = f2bf(v.z); o.w = f2bf(v.w);
    ((ushort4*)db)[k] = o;
  }
}

// ---------------- x [B][C][HW] f32 -> xt [B][HW][C] bf16 ----------------
__global__ __launch_bounds__(256) void k_trans_x(const float* __restrict__ x,
                                                 unsigned short* __restrict__ xt) {
  __shared__ float tile[32][33];
  int pb = blockIdx.x, cb = blockIdx.y, b = blockIdx.z;
  int t = threadIdx.x;
  int c = t >> 3, p4 = (t & 7) * 4;
  float4 v = *(const float4*)(x + (((size_t)b * Cn + cb * 32 + c) * HWn + pb * 32 + p4));
  tile[c][p4 + 0] = v.x; tile[c][p4 + 1] = v.y; tile[c][p4 + 2] = v.z; tile[c][p4 + 3] = v.w;
  __syncthreads();
  int p = t >> 3, c4 = (t & 7) * 4;
  ushort4 o;
  o.x = f2bf(tile[c4 + 0][p]); o.y = f2bf(tile[c4 + 1][p]);
  o.z = f2bf(tile[c4 + 2][p]); o.w = f2bf(tile[c4 + 3][p]);
  *(ushort4*)(xt + (((size_t)b * HWn + pb * 32 + p) * Cn + cb * 32 + c4)) = o;
}

// ---------------- GEMM: C[M][N] = A[M][K] * Bt[N][K]^T + bias ----------------
// 512 threads (8 waves), 2-phase dbuf global_load_lds staging, n-major tile
// order + XCD batch chunking (FETCH 40->7 MB, R11-verified), LDS-transposed
// epilogue, plain stores (NT caused 4x write amplification, R11).
// EPI 0: head-panel out — m-tiles 0-3 (q,k) -> qkh[b][slot][px_ord][32] where
//        slot = isK*8+head, px_ord is w-major for heads 4-7; K pre-scaled KSC.
//        m-tiles 4-5 (v) -> outV[b][px][256] pixel-major.
// EPI 1: f32 [M][N]
template <int EPI>
__global__ __launch_bounds__(512) void k_gemm(const unsigned short* __restrict__ A,
                                              const unsigned short* __restrict__ Bt,
                                              const float* __restrict__ bias,
                                              unsigned short* __restrict__ outB,
                                              float* __restrict__ outF,
                                              unsigned short* __restrict__ outV,
                                              int M, int N, int K, int nm, int nper) {
  __shared__ __align__(16) char SH[EPI ? 67584 : 65536];
  unsigned short* As = (unsigned short*)SH;   // [2][8192]
  unsigned short* Bs = As + 16384;            // [2][8192]
  int t = threadIdx.x;
  int raw = blockIdx.x;
  int chunk = gridDim.x >> 3;
  int wg = (raw & 7) * chunk + (raw >> 3);     // bijective (grid % 8 == 0)
  int b = wg / nper, r = wg % nper;
  int m0 = (r % nm) * 128, n0 = (r / nm) * 128;
  const unsigned short* Bb = Bt + (size_t)b * N * K;
  int lane = t & 63, w = t >> 6;
  int wr = w >> 1, wc = w & 1;
  int g = lane >> 4, q = lane & 15;
  int srow8 = lane >> 3;   // 0..7
  int slot = lane & 7;

  // staging source pointers (k0 added per tile); round i covers rows i*64 + w*8 + srow8
  const unsigned short* Ag[2];
  const unsigned short* Bg[2];
  bool bok[2];
  int ldst[2];
#pragma unroll
  for (int i = 0; i < 2; i++) {
    int row = i * 64 + w * 8 + srow8;
    int cs = slot ^ srow8;                    // row & 7 == srow8
    Ag[i] = A + (size_t)(m0 + row) * K + cs * 8;
    int nr = n0 + row;
    bok[i] = (nr < N);
    Bg[i] = Bb + (size_t)(bok[i] ? nr : (N - 1)) * K + cs * 8;
    ldst[i] = (i * 64 + w * 8) * 64;
  }

  floatx4 z4 = {0.f, 0.f, 0.f, 0.f};
  floatx4 acc[2][4];
#pragma unroll
  for (int i = 0; i < 2; i++)
#pragma unroll
    for (int j = 0; j < 4; j++) acc[i][j] = z4;

  // prologue: stage tile 0
#pragma unroll
  for (int i = 0; i < 2; i++) gload16(Ag[i], &As[ldst[i]]);
#pragma unroll
  for (int i = 0; i < 2; i++) if (bok[i]) gload16(Bg[i], &Bs[ldst[i]]);
  asm volatile("s_waitcnt vmcnt(0)" ::: "memory");
  __syncthreads();

  int cur = 0;
  for (int tt = 0; tt < 4; tt++) {
    if (tt < 3) {   // stage next tile into the other buffer
      int k0 = (tt + 1) * 64;
      int nb = (cur ^ 1) * 8192;
#pragma unroll
      for (int i = 0; i < 2; i++) gload16(Ag[i] + k0, &As[nb + ldst[i]]);
#pragma unroll
      for (int i = 0; i < 2; i++) if (bok[i]) gload16(Bg[i] + k0, &Bs[nb + ldst[i]]);
    }
    int cb = cur * 8192;
#pragma unroll
    for (int kk = 0; kk < 64; kk += 32) {
      short8 af[2], bfr[4];
#pragma unroll
      for (int i = 0; i < 2; i++) {
        int row = wr * 32 + i * 16 + q;
        af[i] = *(const short8*)&As[cb + row * 64 + ((((kk >> 3) + g) ^ (q & 7)) << 3)];
      }
#pragma unroll
      for (int j = 0; j < 4; j++) {
        int row = wc * 64 + j * 16 + q;
        bfr[j] = *(const short8*)&Bs[cb + row * 64 + ((((kk >> 3) + g) ^ (q & 7)) << 3)];
      }
#pragma unroll
      for (int i = 0; i < 2; i++)
#pragma unroll
        for (int j = 0; j < 4; j++)
          acc[i][j] = __builtin_amdgcn_mfma_f32_16x16x32_bf16(af[i], bfr[j], acc[i][j], 0, 0, 0);
    }
    if (tt < 3) {
      asm volatile("s_waitcnt vmcnt(0)" ::: "memory");
      __syncthreads();
      cur ^= 1;
    }
  }

  // ---- LDS-transposed epilogue (dense, coalesced global writes) ----
  __syncthreads();   // all waves done reading As/Bs
  if (EPI == 0) {
    unsigned short* E = (unsigned short*)SH;   // [col 128][16 granules x 8ch], XOR-swizzled
#pragma unroll
    for (int i = 0; i < 2; i++) {
      int ob = m0 + wr * 32 + i * 16 + g * 4;
      float bs0 = bias[ob + 0], bs1 = bias[ob + 1], bs2 = bias[ob + 2], bs3 = bias[ob + 3];
      float sc = (ob >= 256 && ob < 512) ? KSC : 1.0f;
      int lobg = wr * 4 + i * 2 + (g >> 1);
#pragma unroll
      for (int j = 0; j < 4; j++) {
        int lc = wc * 64 + j * 16 + q;
        ushort4 o;
        o.x = f2bf((acc[i][j][0] + bs0) * sc);
        o.y = f2bf((acc[i][j][1] + bs1) * sc);
        o.z = f2bf((acc[i][j][2] + bs2) * sc);
        o.w = f2bf((acc[i][j][3] + bs3) * sc);
        *(ushort4*)&E[lc * 128 + ((lobg ^ (lc & 7)) << 3) + (g & 1) * 4] = o;
      }
    }
    __syncthreads();
    int c = t >> 2, part = t & 3;
    int col = n0 + c;
    if (col < N) {
      int mt = m0 >> 7;            // 0..5
      unsigned short* dst;
      if (mt < 4) {                // q,k head-panels
        int hd = (mt & 1) * 4 + part;
        int sl = (mt >> 1) * 8 + hd;           // isK*8 + head
        int p_ord = (hd >= 4) ? ((col % Wn) * Wn + col / Wn) : col;
        dst = outB + (((size_t)b * 16 + sl) * HWn + p_ord) * 32;
      } else {                     // v pixel-major
        dst = outV + ((size_t)b * HWn + col) * 256 + (m0 - 512) + part * 32;
      }
#pragma unroll
      for (int k2 = part * 4; k2 < part * 4 + 4; k2++) {   // 32 chans = 64B contiguous
        short8 v = *(const short8*)&E[c * 128 + ((k2 ^ (c & 7)) << 3)];
        *(short8*)(dst + (k2 - part * 4) * 8) = v;
      }
    }
  } else {
    float* Ef = (float*)SH;   // [row 128][132]
#pragma unroll
    for (int i = 0; i < 2; i++) {
      int ob = m0 + wr * 32 + i * 16 + g * 4;
      int lob = wr * 32 + i * 16 + g * 4;
      float bs0 = bias[ob + 0], bs1 = bias[ob + 1], bs2 = bias[ob + 2], bs3 = bias[ob + 3];
#pragma unroll
      for (int j = 0; j < 4; j++) {
        int lc = wc * 64 + j * 16 + q;
        Ef[(lob + 0) * 132 + lc] = acc[i][j][0] + bs0;
        Ef[(lob + 1) * 132 + lc] = acc[i][j][1] + bs1;
        Ef[(lob + 2) * 132 + lc] = acc[i][j][2] + bs2;
        Ef[(lob + 3) * 132 + lc] = acc[i][j][3] + bs3;
      }
    }
    __syncthreads();
    int rr = t >> 2, seg = t & 3;
    float* dst = outF + (size_t)b * M * N + (size_t)(m0 + rr) * N + n0;
#pragma unroll
    for (int k2 = 0; k2 < 8; k2++) {
      int col = seg * 32 + k2 * 4;
      if (n0 + col < N) {
        floatx4 v = *(const floatx4*)&Ef[rr * 132 + col];
        *(floatx4*)(dst + col) = v;
      }
    }
  }
}

// ---------------- depthwise 3x3 on v (vb[b][px][256]), output vmt[b][ch][pixel] ----------------
// pass 0: heads 0..3, h-major pixel order; pass 1: heads 4..7, w-major order.
__global__ __launch_bounds__(256) void k_dwconv_t(const unsigned short* __restrict__ vb,
                                                  const float* __restrict__ wdw,
                                                  const float* __restrict__ bdw,
                                                  unsigned short* __restrict__ vmt) {
  __shared__ float wS[1152];
  __shared__ float bS[128];
  __shared__ __align__(16) unsigned short tile[16][140];
  int t = threadIdx.x;
  int pass = blockIdx.y, b = blockIdx.z;
  for (int i = t; i < 1152; i += 256) wS[i] = wdw[pass * 1152 + i];
  if (t < 128) bS[t] = bdw[pass * 128 + t];
  __syncthreads();

  int pi = t >> 4, c8 = (t & 15) * 8;
  int i16 = blockIdx.x * 16 + pi;
  int h, w;
  if (pass == 0) { h = i16 / Wn; w = i16 % Wn; }
  else           { w = i16 / Hn; h = i16 % Hn; }

  const unsigned short* vq = vb + pass * 128 + c8;
  float a[8];
  short8 vc = *(const short8*)(vq + ((size_t)b * HWn + h * Wn + w) * 256);
#pragma unroll
  for (int e = 0; e < 8; e++) a[e] = bf2f((unsigned short)vc[e]) + bS[c8 + e];
#pragma unroll
  for (int ky = 0; ky < 3; ky++) {
    int hh = h + ky - 1;
    if (hh < 0 || hh >= Hn) continue;
#pragma unroll
    for (int kx = 0; kx < 3; kx++) {
      int ww = w + kx - 1;
      if (ww < 0 || ww >= Wn) continue;
      short8 vn = *(const short8*)(vq + ((size_t)b * HWn + hh * Wn + ww) * 256);
#pragma unroll
      for (int e = 0; e < 8; e++) a[e] += bf2f((unsigned short)vn[e]) * wS[(c8 + e) * 9 + ky * 3 + kx];
    }
  }
  short8 o;
#pragma unroll
  for (int e = 0; e < 8; e++) o[e] = (short)f2bf(a[e]);
  *(short8*)&tile[pi][c8] = o;
  __syncthreads();

  int dd = t >> 1, half = t & 1;
  short8 ov;
#pragma unroll
  for (int k2 = 0; k2 < 8; k2++) ov[k2] = (short)tile[half * 8 + k2][dd];
  *(short8*)(vmt + ((size_t)(b * Cn + pass * 128 + dd)) * HWn + blockIdx.x * 16 + half * 8) = ov;
}

// ---------------- stripe attention ----------------
// grid: (stripe 0..7, b*8+hd 0..63), 512 threads (8 waves)
// Q/K from head-panels qkh[b][slot][px_ord][32] -> fully contiguous stripe
// slices for BOTH stripe orientations. V from vmt.
__global__ __launch_bounds__(512) void k_attn(const unsigned short* __restrict__ qkh,
                                              const unsigned short* __restrict__ vmt,
                                              unsigned short* __restrict__ aout) {
  __shared__ __align__(16) unsigned short Ks[12288];  // 24 j * 4 g * 16 q granules
  __shared__ __align__(16) unsigned short Vf[12800];  // 50 Gc * 32 d granules (d swizzled)
  __shared__ __align__(16) unsigned short Pf[4096];   // 8 waves * 4 Gl * 16 q granules
  int s = blockIdx.x;
  int hd = blockIdx.y & 7, b = blockIdx.y >> 3;
  int t = threadIdx.x, lane = t & 63, wv = t >> 6;
  bool wst = (hd >= 4);
  int q = lane & 15, g = lane >> 4;
  int sbase = s * SEQ;

  const unsigned short* qh = qkh + (((size_t)b * 16 + hd) * HWn + sbase) * 32;
  const unsigned short* kh = qkh + (((size_t)b * 16 + 8 + hd) * HWn + sbase) * 32;

  // ---- Q prefetch: all per-wave Q fragments, issued first ----
  short8 qpre[4];
#pragma unroll
  for (int it = 0; it < 4; it++) {
    int qb = it * 8 + wv;
    int qi = qb * 16 + q;
    int qil = (qi < SEQ) ? qi : 391;
    qpre[it] = *(const short8*)(qh + (size_t)qil * 32 + g * 8);
  }

  // ---- stage K keys 0..383, fragment-major (contiguous 64B rows) ----
#pragma unroll
  for (int P = 0; P < 3; P++) {
    int key = P * 128 + (t >> 2);
    int gg = t & 3;
    short8 kv = *(const short8*)(kh + (size_t)key * 32 + gg * 8);
    *(short8*)&Ks[((((key >> 4) * 4 + gg) * 16) + (key & 15)) * 8] = kv;
  }
  // ---- j=24 K fragment (keys 384..391; 392+ masked later) in regs ----
  short8 kf24;
  {
    int key = 384 + q; if (key > 391) key = 391;
    kf24 = *(const short8*)(kh + (size_t)key * 32 + g * 8);
  }
  // ---- stage V fragment-major with d-swizzle ----
  const unsigned short* vg = vmt + ((size_t)(b * Cn + hd * HDIM)) * HWn + sbase;
  for (int idx = t; idx < 1600; idx += 512) {
    int d = idx / 50, Gc = idx % 50;
    short8 vv = *(const short8*)(vg + (size_t)d * HWn + Gc * 8);
    *(short8*)&Vf[(Gc * 32 + (d ^ (Gc & 7))) * 8] = vv;
  }
  __syncthreads();

  floatx4 z4 = {0.f, 0.f, 0.f, 0.f};
  unsigned short* Pw = &Pf[wv * 512];
  int gh = g >> 1, ge = (g & 1) * 4;

#pragma unroll
  for (int it = 0; it < 4; it++) {
    int qb = it * 8 + wv;
    if (qb >= 25) continue;
    int qi = qb * 16 + q;
    int qil = (qi < SEQ) ? qi : 391;
    short8 qf = qpre[it];

    // QK^T (swapped): lane holds S^T[key 4g+r][query q], in log2 units
    floatx4 sacc[25];
#pragma unroll
    for (int j = 0; j < 24; j++) {
      short8 kf = *(const short8*)&Ks[((j * 4 + g) * 16 + q) * 8];
      sacc[j] = __builtin_amdgcn_mfma_f32_16x16x32_bf16(kf, qf, z4, 0, 0, 0);
    }
    sacc[24] = __builtin_amdgcn_mfma_f32_16x16x32_bf16(kf24, qf, z4, 0, 0, 0);
    if (g >= 2) { sacc[24][0] = sacc[24][1] = sacc[24][2] = sacc[24][3] = -3.0e38f; }

    // softmax sans max-subtraction (scores bounded; masked -> exp2 -> 0)
    float sm = 0.f;
#pragma unroll
    for (int j = 0; j < 25; j++) {
      float e0 = EXP2(sacc[j][0]); float e1 = EXP2(sacc[j][1]);
      float e2 = EXP2(sacc[j][2]); float e3 = EXP2(sacc[j][3]);
      sacc[j][0] = e0; sacc[j][1] = e1; sacc[j][2] = e2; sacc[j][3] = e3;
      sm += (e0 + e1) + (e2 + e3);
    }
    sm += __shfl_xor(sm, 16);
    sm += __shfl_xor(sm, 32);
    float rcp = 1.0f / sm;

// jbW is clamped to stay in-bounds textually; the guard keeps semantics.
#define WRITEP(cc) do {                                                        \
    enum { jbW = (2*(cc)+1 < 25) ? (2*(cc)+1) : 24 };                          \
    uint2 wA, wB;                                                              \
    wA.x = cvt_pk_bf16(sacc[2*(cc)][0], sacc[2*(cc)][1]);                      \
    wA.y = cvt_pk_bf16(sacc[2*(cc)][2], sacc[2*(cc)][3]);                      \
    if (2*(cc)+1 < 25) {                                                       \
      wB.x = cvt_pk_bf16(sacc[jbW][0], sacc[jbW][1]);                          \
      wB.y = cvt_pk_bf16(sacc[jbW][2], sacc[jbW][3]);                          \
    } else { wB.x = 0u; wB.y = 0u; }                                           \
    *(uint2*)&Pw[(gh * 16 + q) * 8 + ge] = wA;                                 \
    *(uint2*)&Pw[((2 + gh) * 16 + q) * 8 + ge] = wB;                           \
  } while (0)

    // PV: 13 chunks of 32 keys; P round-trips per-wave LDS, pipelined 1 ahead
    floatx4 o0 = z4, o1 = z4;
    WRITEP(0);
#pragma unroll
    for (int ch = 0; ch < 13; ch++) {
      asm volatile("s_waitcnt lgkmcnt(0)" ::: "memory");
      short8 pfr = *(const short8*)&Pw[(g * 16 + q) * 8];
      int Gc = ch * 4 + g; if (Gc > 49) Gc = 49;
      int sw = Gc & 7;
      short8 vf0 = *(const short8*)&Vf[(Gc * 32 + (q ^ sw)) * 8];
      short8 vf1 = *(const short8*)&Vf[(Gc * 32 + 16 + (q ^ sw)) * 8];
      if (ch < 12) {
        switch (ch + 1) {   // keep sacc indices compile-time after unroll
          case 1: WRITEP(1); break;  case 2: WRITEP(2); break;
          case 3: WRITEP(3); break;  case 4: WRITEP(4); break;
          case 5: WRITEP(5); break;  case 6: WRITEP(6); break;
          case 7: WRITEP(7); break;  case 8: WRITEP(8); break;
          case 9: WRITEP(9); break;  case 10: WRITEP(10); break;
          case 11: WRITEP(11); break; case 12: WRITEP(12); break;
        }
      }
      o0 = __builtin_amdgcn_mfma_f32_16x16x32_bf16(vf0, pfr, o0, 0, 0, 0);
      o1 = __builtin_amdgcn_mfma_f32_16x16x32_bf16(vf1, pfr, o1, 0, 0, 0);
    }
#undef WRITEP

    if (qi < SEQ) {
      int pq = wst ? ((qil % Wn) * Wn + s * 7 + qil / Wn) : (sbase + qil);
      size_t ob = ((size_t)b * HWn + pq) * Cn + hd * HDIM;
      ushort4 u0, u1;
      u0.x = f2bf(o0[0] * rcp); u0.y = f2bf(o0[1] * rcp);
      u0.z = f2bf(o0[2] * rcp); u0.w = f2bf(o0[3] * rcp);
      u1.x = f2bf(o1[0] * rcp); u1.y = f2bf(o1[1] * rcp);
      u1.z = f2bf(o1[2] * rcp); u1.w = f2bf(o1[3] * rcp);
      *(ushort4*)(aout + ob + g * 4) = u0;
      *(ushort4*)(aout + ob + 16 + g * 4) = u1;
    }
  }
}

extern "C" void kernel_launch(void* const* d_in, const int* in_sizes, int n_in,
                              void* d_out, int out_size, void* d_ws, size_t ws_size,
                              hipStream_t stream) {
  const float* x     = (const float*)d_in[0];
  const float* wqkv  = (const float*)d_in[1];
  const float* bqkv  = (const float*)d_in[2];
  const float* wdw   = (const float*)d_in[3];
  const float* bdw   = (const float*)d_in[4];
  const float* wproj = (const float*)d_in[5];
  const float* bproj = (const float*)d_in[6];
  float* out = (float*)d_out;

  unsigned short* xt   = (unsigned short*)d_ws;                    // [B][HW][256] bf16
  unsigned short* wqb  = xt + (size_t)Bn * HWn * Cn;               // [768][256]
  unsigned short* wpb  = wqb + 768 * 256;                          // [256][256]
  unsigned short* qkh  = wpb + 256 * 256;                          // [B][16][HW][32] head-panels
  unsigned short* vb   = qkh + (size_t)Bn * 16 * HWn * 32;         // [B][HW][256] v pixel-major
  unsigned short* vmt  = vb + (size_t)Bn * HWn * Cn;               // [B][256ch][HW]
  unsigned short* aout = vmt + (size_t)Bn * HWn * Cn;              // [B][HW][256]

  k_cvt2<<<dim3(256), 256, 0, stream>>>(wqkv, wproj, wqb, wpb);
  k_trans_x<<<dim3(98, 8, Bn), 256, 0, stream>>>(x, xt);
  k_gemm<0><<<dim3(1200), 512, 0, stream>>>(wqb, xt, bqkv, qkh, nullptr, vb, 768, HWn, 256, 6, 150);
  k_dwconv_t<<<dim3(196, 2, Bn), 256, 0, stream>>>(vb, wdw, bdw, vmt);
  k_attn<<<dim3(NSTR, Bn * NHEADS), 512, 0, stream>>>(qkh, vmt, aout);
  k_gemm<1><<<dim3(400), 512, 0, stream>>>(wpb, aout, bproj, nullptr, out, nullptr, 256, HWn, 256, 2, 50);
}

// Round 14
// 108.154 us; speedup vs baseline: 1.7218x; 1.0030x over previous
//
#include <hip/hip_runtime.h>
#include <hip/hip_bf16.h>
#include <stdint.h>

#define Bn 8
#define Cn 256
#define Hn 56
#define Wn 56
#define HWn 3136
#define NHEADS 8
#define HDIM 32
#define SEQ 392
#define NSTR 8
#define QKV_LD 768
// SCALE * log2(e): K is pre-scaled by this in the qkv-GEMM epilogue so the
// attention softmax can use exp2 with no per-score multiply.
#define KSC (0.17677669529663689f * 1.4426950408889634f)

#if __has_builtin(__builtin_amdgcn_exp2f)
#define EXP2(x) __builtin_amdgcn_exp2f(x)
#else
#define EXP2(x) exp2f(x)
#endif

typedef short short8 __attribute__((ext_vector_type(8)));
typedef float floatx4 __attribute__((ext_vector_type(4)));

__device__ __forceinline__ unsigned short f2bf(float f) {
  union { float f; uint32_t u; } v; v.f = f;
  uint32_t u = v.u;
  u += 0x7fffu + ((u >> 16) & 1u);   // RNE
  return (unsigned short)(u >> 16);
}
__device__ __forceinline__ float bf2f(unsigned short h) {
  union { uint32_t u; float f; } v; v.u = ((uint32_t)h) << 16;
  return v.f;
}
__device__ __forceinline__ uint32_t cvt_pk_bf16(float lo, float hi) {
  uint32_t r;
  asm("v_cvt_pk_bf16_f32 %0, %1, %2" : "=v"(r) : "v"(lo), "v"(hi));
  return r;
}
// async global->LDS, 16B per lane; LDS dest = wave-uniform base + lane*16
__device__ __forceinline__ void gload16(const unsigned short* g, unsigned short* l) {
  __builtin_amdgcn_global_load_lds((const __attribute__((address_space(1))) void*)g,
                                   (__attribute__((address_space(3))) void*)l, 16, 0, 0);
}

// ---------------- convert fp32 -> bf16 (both weight matrices, one launch) ----------------
__global__ __launch_bounds__(256) void k_cvt2(const float* __restrict__ a,
                                              const float* __restrict__ b2,
                                              unsigned short* __restrict__ da,
                                              unsigned short* __restrict__ db) {
  int i = blockIdx.x * 256 + threadIdx.x;   // 65536 float4 slots total
  if (i < 49152) {
    float4 v = ((const float4*)a)[i];
    ushort4 o;
    o.x = f2bf(v.x); o.y = f2bf(v.y); o.z = f2bf(v.z); o.w = f2bf(v.w);
    ((ushort4*)da)[i] = o;
  } else {
    int k = i - 49152;
    float4 v = ((const float4*)b2)[k];
    ushort4 o;
    o.x = f2bf(v.x); o.y = f2bf(v.y); o.z = f2bf(v.z); o.w = f2bf(v.w);
    ((ushort4*)db)[k] = o;
  }
}

// ---------------- x [B][C][HW] f32 -> xt [B][HW][C] bf16 ----------------
__global__ __launch_bounds__(256) void k_trans_x(const float* __restrict__ x,
                                                 unsigned short* __restrict__ xt) {
  __shared__ float tile[32][33];
  int pb = blockIdx.x, cb = blockIdx.y, b = blockIdx.z;
  int t = threadIdx.x;
  int c = t >> 3, p4 = (t & 7) * 4;
  float4 v = *(const float4*)(x + (((size_t)b * Cn + cb * 32 + c) * HWn + pb * 32 + p4));
  tile[c][p4 + 0] = v.x; tile[c][p4 + 1] = v.y; tile[c][p4 + 2] = v.z; tile[c][p4 + 3] = v.w;
  __syncthreads();
  int p = t >> 3, c4 = (t & 7) * 4;
  ushort4 o;
  o.x = f2bf(tile[c4 + 0][p]); o.y = f2bf(tile[c4 + 1][p]);
  o.z = f2bf(tile[c4 + 2][p]); o.w = f2bf(tile[c4 + 3][p]);
  *(ushort4*)(xt + (((size_t)b * HWn + pb * 32 + p) * Cn + cb * 32 + c4)) = o;
}

// ---------------- GEMM: C[M][N] = A[M][K] * Bt[N][K]^T + bias (K == 256) ----------------
// 512 threads (8 waves), DEPTH-2 pipeline with counted vmcnt(4) (T4): tiles
// t and t+1 always in flight, never a full drain in the loop. Loads are
// unconditional (clamped row for n>=N) so per-thread vmcnt counts stay uniform.
// n-major tile order + XCD batch chunking (FETCH 40->7 MB), LDS-transposed
// epilogue, plain stores (NT = 4x write amplification, R11).
// EPI 0: m-tiles 0-3 (q,k) -> qkh[b][slot][px_ord][32], K-rows pre-scaled KSC;
//        m-tiles 4-5 (v) -> outV[b][px][256]. EPI 1: f32 [M][N].
template <int EPI>
__global__ __launch_bounds__(512) void k_gemm(const unsigned short* __restrict__ A,
                                              const unsigned short* __restrict__ Bt,
                                              const float* __restrict__ bias,
                                              unsigned short* __restrict__ outB,
                                              float* __restrict__ outF,
                                              unsigned short* __restrict__ outV,
                                              int M, int N, int nm, int nper) {
  const int K = 256;
  __shared__ __align__(16) char SH[EPI ? 67584 : 65536];
  unsigned short* As = (unsigned short*)SH;   // [2][8192]
  unsigned short* Bs = As + 16384;            // [2][8192]
  int t = threadIdx.x;
  int raw = blockIdx.x;
  int chunk = gridDim.x >> 3;
  int wg = (raw & 7) * chunk + (raw >> 3);     // bijective (grid % 8 == 0)
  int b = wg / nper, r = wg % nper;
  int m0 = (r % nm) * 128, n0 = (r / nm) * 128;
  const unsigned short* Bb = Bt + (size_t)b * N * K;
  int lane = t & 63, w = t >> 6;
  int wr = w >> 1, wc = w & 1;
  int g = lane >> 4, q = lane & 15;
  int srow8 = lane >> 3;   // 0..7
  int slot = lane & 7;

  const unsigned short* Ag[2];
  const unsigned short* Bg[2];
  int ldst[2];
#pragma unroll
  for (int i = 0; i < 2; i++) {
    int row = i * 64 + w * 8 + srow8;
    int cs = slot ^ srow8;                    // row & 7 == srow8
    Ag[i] = A + (size_t)(m0 + row) * K + cs * 8;
    int nr = n0 + row;
    Bg[i] = Bb + (size_t)((nr < N) ? nr : (N - 1)) * K + cs * 8;  // clamp, always load
    ldst[i] = (i * 64 + w * 8) * 64;
  }

  floatx4 z4 = {0.f, 0.f, 0.f, 0.f};
  floatx4 acc[2][4];
#pragma unroll
  for (int i = 0; i < 2; i++)
#pragma unroll
    for (int j = 0; j < 4; j++) acc[i][j] = z4;

#define STAGE(kt, off) do {                                                    \
    _Pragma("unroll")                                                          \
    for (int i = 0; i < 2; i++) gload16(Ag[i] + (kt) * 64, &As[(off) + ldst[i]]); \
    _Pragma("unroll")                                                          \
    for (int i = 0; i < 2; i++) gload16(Bg[i] + (kt) * 64, &Bs[(off) + ldst[i]]); \
  } while (0)

#define COMPUTE(off) do {                                                      \
    _Pragma("unroll")                                                          \
    for (int kk = 0; kk < 64; kk += 32) {                                      \
      short8 af[2], bfr[4];                                                    \
      _Pragma("unroll")                                                        \
      for (int i = 0; i < 2; i++) {                                            \
        int row = wr * 32 + i * 16 + q;                                        \
        af[i] = *(const short8*)&As[(off) + row * 64 + ((((kk >> 3) + g) ^ (q & 7)) << 3)]; \
      }                                                                        \
      _Pragma("unroll")                                                        \
      for (int j = 0; j < 4; j++) {                                            \
        int row = wc * 64 + j * 16 + q;                                        \
        bfr[j] = *(const short8*)&Bs[(off) + row * 64 + ((((kk >> 3) + g) ^ (q & 7)) << 3)]; \
      }                                                                        \
      _Pragma("unroll")                                                        \
      for (int i = 0; i < 2; i++)                                              \
        _Pragma("unroll")                                                      \
        for (int j = 0; j < 4; j++)                                            \
          acc[i][j] = __builtin_amdgcn_mfma_f32_16x16x32_bf16(af[i], bfr[j], acc[i][j], 0, 0, 0); \
    }                                                                          \
  } while (0)

  // depth-2 pipeline over the 4 K-tiles
  STAGE(0, 0);
  STAGE(1, 8192);
  asm volatile("s_waitcnt vmcnt(4)" ::: "memory");   // tile 0 landed
  __syncthreads();
  COMPUTE(0);
  __syncthreads();
  STAGE(2, 0);
  asm volatile("s_waitcnt vmcnt(4)" ::: "memory");   // tile 1 landed
  __syncthreads();
  COMPUTE(8192);
  __syncthreads();
  STAGE(3, 8192);
  asm volatile("s_waitcnt vmcnt(4)" ::: "memory");   // tile 2 landed
  __syncthreads();
  COMPUTE(0);
  asm volatile("s_waitcnt vmcnt(0)" ::: "memory");   // tile 3 landed
  __syncthreads();
  COMPUTE(8192);
#undef STAGE
#undef COMPUTE

  // ---- LDS-transposed epilogue (dense, coalesced global writes) ----
  __syncthreads();   // all waves done reading As/Bs
  if (EPI == 0) {
    unsigned short* E = (unsigned short*)SH;   // [col 128][16 granules x 8ch], XOR-swizzled
#pragma unroll
    for (int i = 0; i < 2; i++) {
      int ob = m0 + wr * 32 + i * 16 + g * 4;
      float bs0 = bias[ob + 0], bs1 = bias[ob + 1], bs2 = bias[ob + 2], bs3 = bias[ob + 3];
      float sc = (ob >= 256 && ob < 512) ? KSC : 1.0f;
      int lobg = wr * 4 + i * 2 + (g >> 1);
#pragma unroll
      for (int j = 0; j < 4; j++) {
        int lc = wc * 64 + j * 16 + q;
        ushort4 o;
        o.x = f2bf((acc[i][j][0] + bs0) * sc);
        o.y = f2bf((acc[i][j][1] + bs1) * sc);
        o.z = f2bf((acc[i][j][2] + bs2) * sc);
        o.w = f2bf((acc[i][j][3] + bs3) * sc);
        *(ushort4*)&E[lc * 128 + ((lobg ^ (lc & 7)) << 3) + (g & 1) * 4] = o;
      }
    }
    __syncthreads();
    int c = t >> 2, part = t & 3;
    int col = n0 + c;
    if (col < N) {
      int mt = m0 >> 7;            // 0..5
      unsigned short* dst;
      if (mt < 4) {                // q,k head-panels
        int hd = (mt & 1) * 4 + part;
        int sl = (mt >> 1) * 8 + hd;           // isK*8 + head
        int p_ord = (hd >= 4) ? ((col % Wn) * Wn + col / Wn) : col;
        dst = outB + (((size_t)b * 16 + sl) * HWn + p_ord) * 32;
      } else {                     // v pixel-major
        dst = outV + ((size_t)b * HWn + col) * 256 + (m0 - 512) + part * 32;
      }
#pragma unroll
      for (int k2 = part * 4; k2 < part * 4 + 4; k2++) {   // 32 chans = 64B contiguous
        short8 v = *(const short8*)&E[c * 128 + ((k2 ^ (c & 7)) << 3)];
        *(short8*)(dst + (k2 - part * 4) * 8) = v;
      }
    }
  } else {
    float* Ef = (float*)SH;   // [row 128][132]
#pragma unroll
    for (int i = 0; i < 2; i++) {
      int ob = m0 + wr * 32 + i * 16 + g * 4;
      int lob = wr * 32 + i * 16 + g * 4;
      float bs0 = bias[ob + 0], bs1 = bias[ob + 1], bs2 = bias[ob + 2], bs3 = bias[ob + 3];
#pragma unroll
      for (int j = 0; j < 4; j++) {
        int lc = wc * 64 + j * 16 + q;
        Ef[(lob + 0) * 132 + lc] = acc[i][j][0] + bs0;
        Ef[(lob + 1) * 132 + lc] = acc[i][j][1] + bs1;
        Ef[(lob + 2) * 132 + lc] = acc[i][j][2] + bs2;
        Ef[(lob + 3) * 132 + lc] = acc[i][j][3] + bs3;
      }
    }
    __syncthreads();
    int rr = t >> 2, seg = t & 3;
    float* dst = outF + (size_t)b * M * N + (size_t)(m0 + rr) * N + n0;
#pragma unroll
    for (int k2 = 0; k2 < 8; k2++) {
      int col = seg * 32 + k2 * 4;
      if (n0 + col < N) {
        floatx4 v = *(const floatx4*)&Ef[rr * 132 + col];
        *(floatx4*)(dst + col) = v;
      }
    }
  }
}

// ---------------- depthwise 3x3 on v (vb[b][px][256]), output vmt[b][ch][pixel] ----------------
// pass 0: heads 0..3, h-major pixel order; pass 1: heads 4..7, w-major order.
__global__ __launch_bounds__(256) void k_dwconv_t(const unsigned short* __restrict__ vb,
                                                  const float* __restrict__ wdw,
                                                  const float* __restrict__ bdw,
                                                  unsigned short* __restrict__ vmt) {
  __shared__ float wS[1152];
  __shared__ float bS[128];
  __shared__ __align__(16) unsigned short tile[16][140];
  int t = threadIdx.x;
  int pass = blockIdx.y, b = blockIdx.z;
  for (int i = t; i < 1152; i += 256) wS[i] = wdw[pass * 1152 + i];
  if (t < 128) bS[t] = bdw[pass * 128 + t];
  __syncthreads();

  int pi = t >> 4, c8 = (t & 15) * 8;
  int i16 = blockIdx.x * 16 + pi;
  int h, w;
  if (pass == 0) { h = i16 / Wn; w = i16 % Wn; }
  else           { w = i16 / Hn; h = i16 % Hn; }

  const unsigned short* vq = vb + pass * 128 + c8;
  float a[8];
  short8 vc = *(const short8*)(vq + ((size_t)b * HWn + h * Wn + w) * 256);
#pragma unroll
  for (int e = 0; e < 8; e++) a[e] = bf2f((unsigned short)vc[e]) + bS[c8 + e];
#pragma unroll
  for (int ky = 0; ky < 3; ky++) {
    int hh = h + ky - 1;
    if (hh < 0 || hh >= Hn) continue;
#pragma unroll
    for (int kx = 0; kx < 3; kx++) {
      int ww = w + kx - 1;
      if (ww < 0 || ww >= Wn) continue;
      short8 vn = *(const short8*)(vq + ((size_t)b * HWn + hh * Wn + ww) * 256);
#pragma unroll
      for (int e = 0; e < 8; e++) a[e] += bf2f((unsigned short)vn[e]) * wS[(c8 + e) * 9 + ky * 3 + kx];
    }
  }
  short8 o;
#pragma unroll
  for (int e = 0; e < 8; e++) o[e] = (short)f2bf(a[e]);
  *(short8*)&tile[pi][c8] = o;
  __syncthreads();

  int dd = t >> 1, half = t & 1;
  short8 ov;
#pragma unroll
  for (int k2 = 0; k2 < 8; k2++) ov[k2] = (short)tile[half * 8 + k2][dd];
  *(short8*)(vmt + ((size_t)(b * Cn + pass * 128 + dd)) * HWn + blockIdx.x * 16 + half * 8) = ov;
}

// ---------------- stripe attention ----------------
// grid: (stripe 0..7, b*8+hd 0..63), 512 threads (8 waves)
// Q/K from head-panels qkh[b][slot][px_ord][32] -> fully contiguous stripe
// slices for BOTH stripe orientations. V from vmt.
__global__ __launch_bounds__(512) void k_attn(const unsigned short* __restrict__ qkh,
                                              const unsigned short* __restrict__ vmt,
                                              unsigned short* __restrict__ aout) {
  __shared__ __align__(16) unsigned short Ks[12288];  // 24 j * 4 g * 16 q granules
  __shared__ __align__(16) unsigned short Vf[12800];  // 50 Gc * 32 d granules (d swizzled)
  __shared__ __align__(16) unsigned short Pf[4096];   // 8 waves * 4 Gl * 16 q granules
  int s = blockIdx.x;
  int hd = blockIdx.y & 7, b = blockIdx.y >> 3;
  int t = threadIdx.x, lane = t & 63, wv = t >> 6;
  bool wst = (hd >= 4);
  int q = lane & 15, g = lane >> 4;
  int sbase = s * SEQ;

  const unsigned short* qh = qkh + (((size_t)b * 16 + hd) * HWn + sbase) * 32;
  const unsigned short* kh = qkh + (((size_t)b * 16 + 8 + hd) * HWn + sbase) * 32;

  // ---- Q prefetch: all per-wave Q fragments, issued first ----
  short8 qpre[4];
#pragma unroll
  for (int it = 0; it < 4; it++) {
    int qb = it * 8 + wv;
    int qi = qb * 16 + q;
    int qil = (qi < SEQ) ? qi : 391;
    qpre[it] = *(const short8*)(qh + (size_t)qil * 32 + g * 8);
  }

  // ---- stage K keys 0..383, fragment-major (contiguous 64B rows) ----
#pragma unroll
  for (int P = 0; P < 3; P++) {
    int key = P * 128 + (t >> 2);
    int gg = t & 3;
    short8 kv = *(const short8*)(kh + (size_t)key * 32 + gg * 8);
    *(short8*)&Ks[((((key >> 4) * 4 + gg) * 16) + (key & 15)) * 8] = kv;
  }
  // ---- j=24 K fragment (keys 384..391; 392+ masked later) in regs ----
  short8 kf24;
  {
    int key = 384 + q; if (key > 391) key = 391;
    kf24 = *(const short8*)(kh + (size_t)key * 32 + g * 8);
  }
  // ---- stage V fragment-major with d-swizzle ----
  const unsigned short* vg = vmt + ((size_t)(b * Cn + hd * HDIM)) * HWn + sbase;
  for (int idx = t; idx < 1600; idx += 512) {
    int d = idx / 50, Gc = idx % 50;
    short8 vv = *(const short8*)(vg + (size_t)d * HWn + Gc * 8);
    *(short8*)&Vf[(Gc * 32 + (d ^ (Gc & 7))) * 8] = vv;
  }
  __syncthreads();

  floatx4 z4 = {0.f, 0.f, 0.f, 0.f};
  unsigned short* Pw = &Pf[wv * 512];
  int gh = g >> 1, ge = (g & 1) * 4;

#pragma unroll
  for (int it = 0; it < 4; it++) {
    int qb = it * 8 + wv;
    if (qb >= 25) continue;
    int qi = qb * 16 + q;
    int qil = (qi < SEQ) ? qi : 391;
    short8 qf = qpre[it];

    // QK^T (swapped): lane holds S^T[key 4g+r][query q], in log2 units
    floatx4 sacc[25];
#pragma unroll
    for (int j = 0; j < 24; j++) {
      short8 kf = *(const short8*)&Ks[((j * 4 + g) * 16 + q) * 8];
      sacc[j] = __builtin_amdgcn_mfma_f32_16x16x32_bf16(kf, qf, z4, 0, 0, 0);
    }
    sacc[24] = __builtin_amdgcn_mfma_f32_16x16x32_bf16(kf24, qf, z4, 0, 0, 0);
    if (g >= 2) { sacc[24][0] = sacc[24][1] = sacc[24][2] = sacc[24][3] = -3.0e38f; }

    // softmax sans max-subtraction (scores bounded; masked -> exp2 -> 0)
    float sm = 0.f;
#pragma unroll
    for (int j = 0; j < 25; j++) {
      float e0 = EXP2(sacc[j][0]); float e1 = EXP2(sacc[j][1]);
      float e2 = EXP2(sacc[j][2]); float e3 = EXP2(sacc[j][3]);
      sacc[j][0] = e0; sacc[j][1] = e1; sacc[j][2] = e2; sacc[j][3] = e3;
      sm += (e0 + e1) + (e2 + e3);
    }
    sm += __shfl_xor(sm, 16);
    sm += __shfl_xor(sm, 32);
    float rcp = 1.0f / sm;

// jbW is clamped to stay in-bounds textually; the guard keeps semantics.
#define WRITEP(cc) do {                                                        \
    enum { jbW = (2*(cc)+1 < 25) ? (2*(cc)+1) : 24 };                          \
    uint2 wA, wB;                                                              \
    wA.x = cvt_pk_bf16(sacc[2*(cc)][0], sacc[2*(cc)][1]);                      \
    wA.y = cvt_pk_bf16(sacc[2*(cc)][2], sacc[2*(cc)][3]);                      \
    if (2*(cc)+1 < 25) {                                                       \
      wB.x = cvt_pk_bf16(sacc[jbW][0], sacc[jbW][1]);                          \
      wB.y = cvt_pk_bf16(sacc[jbW][2], sacc[jbW][3]);                          \
    } else { wB.x = 0u; wB.y = 0u; }                                           \
    *(uint2*)&Pw[(gh * 16 + q) * 8 + ge] = wA;                                 \
    *(uint2*)&Pw[((2 + gh) * 16 + q) * 8 + ge] = wB;                           \
  } while (0)

    // PV: 13 chunks of 32 keys; P round-trips per-wave LDS, pipelined 1 ahead
    floatx4 o0 = z4, o1 = z4;
    WRITEP(0);
#pragma unroll
    for (int ch = 0; ch < 13; ch++) {
      asm volatile("s_waitcnt lgkmcnt(0)" ::: "memory");
      short8 pfr = *(const short8*)&Pw[(g * 16 + q) * 8];
      int Gc = ch * 4 + g; if (Gc > 49) Gc = 49;
      int sw = Gc & 7;
      short8 vf0 = *(const short8*)&Vf[(Gc * 32 + (q ^ sw)) * 8];
      short8 vf1 = *(const short8*)&Vf[(Gc * 32 + 16 + (q ^ sw)) * 8];
      if (ch < 12) {
        switch (ch + 1) {   // keep sacc indices compile-time after unroll
          case 1: WRITEP(1); break;  case 2: WRITEP(2); break;
          case 3: WRITEP(3); break;  case 4: WRITEP(4); break;
          case 5: WRITEP(5); break;  case 6: WRITEP(6); break;
          case 7: WRITEP(7); break;  case 8: WRITEP(8); break;
          case 9: WRITEP(9); break;  case 10: WRITEP(10); break;
          case 11: WRITEP(11); break; case 12: WRITEP(12); break;
        }
      }
      o0 = __builtin_amdgcn_mfma_f32_16x16x32_bf16(vf0, pfr, o0, 0, 0, 0);
      o1 = __builtin_amdgcn_mfma_f32_16x16x32_bf16(vf1, pfr, o1, 0, 0, 0);
    }
#undef WRITEP

    if (qi < SEQ) {
      int pq = wst ? ((qil % Wn) * Wn + s * 7 + qil / Wn) : (sbase + qil);
      size_t ob = ((size_t)b * HWn + pq) * Cn + hd * HDIM;
      ushort4 u0, u1;
      u0.x = f2bf(o0[0] * rcp); u0.y = f2bf(o0[1] * rcp);
      u0.z = f2bf(o0[2] * rcp); u0.w = f2bf(o0[3] * rcp);
      u1.x = f2bf(o1[0] * rcp); u1.y = f2bf(o1[1] * rcp);
      u1.z = f2bf(o1[2] * rcp); u1.w = f2bf(o1[3] * rcp);
      *(ushort4*)(aout + ob + g * 4) = u0;
      *(ushort4*)(aout + ob + 16 + g * 4) = u1;
    }
  }
}

extern "C" void kernel_launch(void* const* d_in, const int* in_sizes, int n_in,
                              void* d_out, int out_size, void* d_ws, size_t ws_size,
                              hipStream_t stream) {
  const float* x     = (const float*)d_in[0];
  const float* wqkv  = (const float*)d_in[1];
  const float* bqkv  = (const float*)d_in[2];
  const float* wdw   = (const float*)d_in[3];
  const float* bdw   = (const float*)d_in[4];
  const float* wproj = (const float*)d_in[5];
  const float* bproj = (const float*)d_in[6];
  float* out = (float*)d_out;

  unsigned short* xt   = (unsigned short*)d_ws;                    // [B][HW][256] bf16
  unsigned short* wqb  = xt + (size_t)Bn * HWn * Cn;               // [768][256]
  unsigned short* wpb  = wqb + 768 * 256;                          // [256][256]
  unsigned short* qkh  = wpb + 256 * 256;                          // [B][16][HW][32] head-panels
  unsigned short* vb   = qkh + (size_t)Bn * 16 * HWn * 32;         // [B][HW][256] v pixel-major
  unsigned short* vmt  = vb + (size_t)Bn * HWn * Cn;               // [B][256ch][HW]
  unsigned short* aout = vmt + (size_t)Bn * HWn * Cn;              // [B][HW][256]

  k_cvt2<<<dim3(256), 256, 0, stream>>>(wqkv, wproj, wqb, wpb);
  k_trans_x<<<dim3(98, 8, Bn), 256, 0, stream>>>(x, xt);
  k_gemm<0><<<dim3(1200), 512, 0, stream>>>(wqb, xt, bqkv, qkh, nullptr, vb, 768, HWn, 6, 150);
  k_dwconv_t<<<dim3(196, 2, Bn), 256, 0, stream>>>(vb, wdw, bdw, vmt);
  k_attn<<<dim3(NSTR, Bn * NHEADS), 512, 0, stream>>>(qkh, vmt, aout);
  k_gemm<1><<<dim3(400), 512, 0, stream>>>(wpb, aout, bproj, nullptr, out, nullptr, 256, HWn, 2, 50);
}

// Round 15
// 105.586 us; speedup vs baseline: 1.7636x; 1.0243x over previous
//
#include <hip/hip_runtime.h>
#include <hip/hip_bf16.h>
#include <stdint.h>

#define Bn 8
#define Cn 256
#define Hn 56
#define Wn 56
#define HWn 3136
#define NHEADS 8
#define HDIM 32
#define SEQ 392
#define NSTR 8
#define QKV_LD 768
// SCALE * log2(e): K is pre-scaled by this in the qkv-GEMM epilogue so the
// attention softmax can use exp2 with no per-score multiply.
#define KSC (0.17677669529663689f * 1.4426950408889634f)

#if __has_builtin(__builtin_amdgcn_exp2f)
#define EXP2(x) __builtin_amdgcn_exp2f(x)
#else
#define EXP2(x) exp2f(x)
#endif

typedef short short8 __attribute__((ext_vector_type(8)));
typedef float floatx4 __attribute__((ext_vector_type(4)));

__device__ __forceinline__ unsigned short f2bf(float f) {
  union { float f; uint32_t u; } v; v.f = f;
  uint32_t u = v.u;
  u += 0x7fffu + ((u >> 16) & 1u);   // RNE
  return (unsigned short)(u >> 16);
}
__device__ __forceinline__ float bf2f(unsigned short h) {
  union { uint32_t u; float f; } v; v.u = ((uint32_t)h) << 16;
  return v.f;
}
__device__ __forceinline__ uint32_t cvt_pk_bf16(float lo, float hi) {
  uint32_t r;
  asm("v_cvt_pk_bf16_f32 %0, %1, %2" : "=v"(r) : "v"(lo), "v"(hi));
  return r;
}
// async global->LDS, 16B per lane; LDS dest = wave-uniform base + lane*16
__device__ __forceinline__ void gload16(const unsigned short* g, unsigned short* l) {
  __builtin_amdgcn_global_load_lds((const __attribute__((address_space(1))) void*)g,
                                   (__attribute__((address_space(3))) void*)l, 16, 0, 0);
}

// ---------------- prep: weight cvt (blocks 0..255) + x transpose (blocks 256+) ----------------
__global__ __launch_bounds__(256) void k_prep(const float* __restrict__ wa,
                                              const float* __restrict__ wb,
                                              unsigned short* __restrict__ da,
                                              unsigned short* __restrict__ db,
                                              const float* __restrict__ x,
                                              unsigned short* __restrict__ xt) {
  int bx = blockIdx.x;
  int t = threadIdx.x;
  if (bx < 256) {
    int i = bx * 256 + t;   // 65536 float4 slots total
    if (i < 49152) {
      float4 v = ((const float4*)wa)[i];
      ushort4 o;
      o.x = f2bf(v.x); o.y = f2bf(v.y); o.z = f2bf(v.z); o.w = f2bf(v.w);
      ((ushort4*)da)[i] = o;
    } else {
      int k = i - 49152;
      float4 v = ((const float4*)wb)[k];
      ushort4 o;
      o.x = f2bf(v.x); o.y = f2bf(v.y); o.z = f2bf(v.z); o.w = f2bf(v.w);
      ((ushort4*)db)[k] = o;
    }
    return;
  }
  __shared__ float tile[32][33];
  int tx = bx - 256;
  int pb = tx % 98, cb = (tx / 98) & 7, b = tx / 784;
  int c = t >> 3, p4 = (t & 7) * 4;
  float4 v = *(const float4*)(x + (((size_t)b * Cn + cb * 32 + c) * HWn + pb * 32 + p4));
  tile[c][p4 + 0] = v.x; tile[c][p4 + 1] = v.y; tile[c][p4 + 2] = v.z; tile[c][p4 + 3] = v.w;
  __syncthreads();
  int p = t >> 3, c4 = (t & 7) * 4;
  ushort4 o;
  o.x = f2bf(tile[c4 + 0][p]); o.y = f2bf(tile[c4 + 1][p]);
  o.z = f2bf(tile[c4 + 2][p]); o.w = f2bf(tile[c4 + 3][p]);
  *(ushort4*)(xt + (((size_t)b * HWn + pb * 32 + p) * Cn + cb * 32 + c4)) = o;
}

// ---------------- GEMM: C[M][N] = A[M][K] * Bt[N][K]^T + bias (K == 256) ----------------
// 512 threads (8 waves), depth-2 counted-vmcnt pipeline, n-major tile order +
// XCD batch chunking (FETCH 40->7 MB, R11), LDS-transposed epilogue, plain
// stores (NT = 4x write amplification, R11).
// EPI 0: m-tiles 0-3 (q,k) -> qkh[b][slot][px_ord][32], K-rows pre-scaled KSC;
//        m-tiles 4-5 (v) -> outV[b][px][256]. EPI 1: f32 [M][N].
template <int EPI>
__global__ __launch_bounds__(512) void k_gemm(const unsigned short* __restrict__ A,
                                              const unsigned short* __restrict__ Bt,
                                              const float* __restrict__ bias,
                                              unsigned short* __restrict__ outB,
                                              float* __restrict__ outF,
                                              unsigned short* __restrict__ outV,
                                              int M, int N, int nm, int nper) {
  const int K = 256;
  __shared__ __align__(16) char SH[EPI ? 67584 : 65536];
  unsigned short* As = (unsigned short*)SH;   // [2][8192]
  unsigned short* Bs = As + 16384;            // [2][8192]
  int t = threadIdx.x;
  int raw = blockIdx.x;
  int chunk = gridDim.x >> 3;
  int wg = (raw & 7) * chunk + (raw >> 3);     // bijective (grid % 8 == 0)
  int b = wg / nper, r = wg % nper;
  int m0 = (r % nm) * 128, n0 = (r / nm) * 128;
  const unsigned short* Bb = Bt + (size_t)b * N * K;
  int lane = t & 63, w = t >> 6;
  int wr = w >> 1, wc = w & 1;
  int g = lane >> 4, q = lane & 15;
  int srow8 = lane >> 3;   // 0..7
  int slot = lane & 7;

  const unsigned short* Ag[2];
  const unsigned short* Bg[2];
  int ldst[2];
#pragma unroll
  for (int i = 0; i < 2; i++) {
    int row = i * 64 + w * 8 + srow8;
    int cs = slot ^ srow8;                    // row & 7 == srow8
    Ag[i] = A + (size_t)(m0 + row) * K + cs * 8;
    int nr = n0 + row;
    Bg[i] = Bb + (size_t)((nr < N) ? nr : (N - 1)) * K + cs * 8;  // clamp, always load
    ldst[i] = (i * 64 + w * 8) * 64;
  }

  floatx4 z4 = {0.f, 0.f, 0.f, 0.f};
  floatx4 acc[2][4];
#pragma unroll
  for (int i = 0; i < 2; i++)
#pragma unroll
    for (int j = 0; j < 4; j++) acc[i][j] = z4;

#define STAGE(kt, off) do {                                                    \
    _Pragma("unroll")                                                          \
    for (int i = 0; i < 2; i++) gload16(Ag[i] + (kt) * 64, &As[(off) + ldst[i]]); \
    _Pragma("unroll")                                                          \
    for (int i = 0; i < 2; i++) gload16(Bg[i] + (kt) * 64, &Bs[(off) + ldst[i]]); \
  } while (0)

#define COMPUTE(off) do {                                                      \
    _Pragma("unroll")                                                          \
    for (int kk = 0; kk < 64; kk += 32) {                                      \
      short8 af[2], bfr[4];                                                    \
      _Pragma("unroll")                                                        \
      for (int i = 0; i < 2; i++) {                                            \
        int row = wr * 32 + i * 16 + q;                                        \
        af[i] = *(const short8*)&As[(off) + row * 64 + ((((kk >> 3) + g) ^ (q & 7)) << 3)]; \
      }                                                                        \
      _Pragma("unroll")                                                        \
      for (int j = 0; j < 4; j++) {                                            \
        int row = wc * 64 + j * 16 + q;                                        \
        bfr[j] = *(const short8*)&Bs[(off) + row * 64 + ((((kk >> 3) + g) ^ (q & 7)) << 3)]; \
      }                                                                        \
      _Pragma("unroll")                                                        \
      for (int i = 0; i < 2; i++)                                              \
        _Pragma("unroll")                                                      \
        for (int j = 0; j < 4; j++)                                            \
          acc[i][j] = __builtin_amdgcn_mfma_f32_16x16x32_bf16(af[i], bfr[j], acc[i][j], 0, 0, 0); \
    }                                                                          \
  } while (0)

  // depth-2 pipeline over the 4 K-tiles
  STAGE(0, 0);
  STAGE(1, 8192);
  asm volatile("s_waitcnt vmcnt(4)" ::: "memory");   // tile 0 landed
  __syncthreads();
  COMPUTE(0);
  __syncthreads();
  STAGE(2, 0);
  asm volatile("s_waitcnt vmcnt(4)" ::: "memory");   // tile 1 landed
  __syncthreads();
  COMPUTE(8192);
  __syncthreads();
  STAGE(3, 8192);
  asm volatile("s_waitcnt vmcnt(4)" ::: "memory");   // tile 2 landed
  __syncthreads();
  COMPUTE(0);
  asm volatile("s_waitcnt vmcnt(0)" ::: "memory");   // tile 3 landed
  __syncthreads();
  COMPUTE(8192);
#undef STAGE
#undef COMPUTE

  // ---- LDS-transposed epilogue (dense, coalesced global writes) ----
  __syncthreads();   // all waves done reading As/Bs
  if (EPI == 0) {
    unsigned short* E = (unsigned short*)SH;   // [col 128][16 granules x 8ch], XOR-swizzled
#pragma unroll
    for (int i = 0; i < 2; i++) {
      int ob = m0 + wr * 32 + i * 16 + g * 4;
      float bs0 = bias[ob + 0], bs1 = bias[ob + 1], bs2 = bias[ob + 2], bs3 = bias[ob + 3];
      float sc = (ob >= 256 && ob < 512) ? KSC : 1.0f;
      int lobg = wr * 4 + i * 2 + (g >> 1);
#pragma unroll
      for (int j = 0; j < 4; j++) {
        int lc = wc * 64 + j * 16 + q;
        ushort4 o;
        o.x = f2bf((acc[i][j][0] + bs0) * sc);
        o.y = f2bf((acc[i][j][1] + bs1) * sc);
        o.z = f2bf((acc[i][j][2] + bs2) * sc);
        o.w = f2bf((acc[i][j][3] + bs3) * sc);
        *(ushort4*)&E[lc * 128 + ((lobg ^ (lc & 7)) << 3) + (g & 1) * 4] = o;
      }
    }
    __syncthreads();
    int c = t >> 2, part = t & 3;
    int col = n0 + c;
    if (col < N) {
      int mt = m0 >> 7;            // 0..5
      unsigned short* dst;
      if (mt < 4) {                // q,k head-panels
        int hd = (mt & 1) * 4 + part;
        int sl = (mt >> 1) * 8 + hd;           // isK*8 + head
        int p_ord = (hd >= 4) ? ((col % Wn) * Wn + col / Wn) : col;
        dst = outB + (((size_t)b * 16 + sl) * HWn + p_ord) * 32;
      } else {                     // v pixel-major
        dst = outV + ((size_t)b * HWn + col) * 256 + (m0 - 512) + part * 32;
      }
#pragma unroll
      for (int k2 = part * 4; k2 < part * 4 + 4; k2++) {   // 32 chans = 64B contiguous
        short8 v = *(const short8*)&E[c * 128 + ((k2 ^ (c & 7)) << 3)];
        *(short8*)(dst + (k2 - part * 4) * 8) = v;
      }
    }
  } else {
    float* Ef = (float*)SH;   // [row 128][132]
#pragma unroll
    for (int i = 0; i < 2; i++) {
      int ob = m0 + wr * 32 + i * 16 + g * 4;
      int lob = wr * 32 + i * 16 + g * 4;
      float bs0 = bias[ob + 0], bs1 = bias[ob + 1], bs2 = bias[ob + 2], bs3 = bias[ob + 3];
#pragma unroll
      for (int j = 0; j < 4; j++) {
        int lc = wc * 64 + j * 16 + q;
        Ef[(lob + 0) * 132 + lc] = acc[i][j][0] + bs0;
        Ef[(lob + 1) * 132 + lc] = acc[i][j][1] + bs1;
        Ef[(lob + 2) * 132 + lc] = acc[i][j][2] + bs2;
        Ef[(lob + 3) * 132 + lc] = acc[i][j][3] + bs3;
      }
    }
    __syncthreads();
    int rr = t >> 2, seg = t & 3;
    float* dst = outF + (size_t)b * M * N + (size_t)(m0 + rr) * N + n0;
#pragma unroll
    for (int k2 = 0; k2 < 8; k2++) {
      int col = seg * 32 + k2 * 4;
      if (n0 + col < N) {
        floatx4 v = *(const floatx4*)&Ef[rr * 132 + col];
        *(floatx4*)(dst + col) = v;
      }
    }
  }
}

// ---------------- depthwise 3x3 on v (vb[b][px][256]), output vmt[b][ch][pixel] ----------------
// pass 0: heads 0..3, h-major pixel order; pass 1: heads 4..7, w-major order.
__global__ __launch_bounds__(256) void k_dwconv_t(const unsigned short* __restrict__ vb,
                                                  const float* __restrict__ wdw,
                                                  const float* __restrict__ bdw,
                                                  unsigned short* __restrict__ vmt) {
  __shared__ float wS[1152];
  __shared__ float bS[128];
  __shared__ __align__(16) unsigned short tile[16][140];
  int t = threadIdx.x;
  int pass = blockIdx.y, b = blockIdx.z;
  for (int i = t; i < 1152; i += 256) wS[i] = wdw[pass * 1152 + i];
  if (t < 128) bS[t] = bdw[pass * 128 + t];
  __syncthreads();

  int pi = t >> 4, c8 = (t & 15) * 8;
  int i16 = blockIdx.x * 16 + pi;
  int h, w;
  if (pass == 0) { h = i16 / Wn; w = i16 % Wn; }
  else           { w = i16 / Hn; h = i16 % Hn; }

  const unsigned short* vq = vb + pass * 128 + c8;
  float a[8];
  short8 vc = *(const short8*)(vq + ((size_t)b * HWn + h * Wn + w) * 256);
#pragma unroll
  for (int e = 0; e < 8; e++) a[e] = bf2f((unsigned short)vc[e]) + bS[c8 + e];
#pragma unroll
  for (int ky = 0; ky < 3; ky++) {
    int hh = h + ky - 1;
    if (hh < 0 || hh >= Hn) continue;
#pragma unroll
    for (int kx = 0; kx < 3; kx++) {
      int ww = w + kx - 1;
      if (ww < 0 || ww >= Wn) continue;
      short8 vn = *(const short8*)(vq + ((size_t)b * HWn + hh * Wn + ww) * 256);
#pragma unroll
      for (int e = 0; e < 8; e++) a[e] += bf2f((unsigned short)vn[e]) * wS[(c8 + e) * 9 + ky * 3 + kx];
    }
  }
  short8 o;
#pragma unroll
  for (int e = 0; e < 8; e++) o[e] = (short)f2bf(a[e]);
  *(short8*)&tile[pi][c8] = o;
  __syncthreads();

  int dd = t >> 1, half = t & 1;
  short8 ov;
#pragma unroll
  for (int k2 = 0; k2 < 8; k2++) ov[k2] = (short)tile[half * 8 + k2][dd];
  *(short8*)(vmt + ((size_t)(b * Cn + pass * 128 + dd)) * HWn + blockIdx.x * 16 + half * 8) = ov;
}

// ---------------- stripe attention ----------------
// grid: (stripe 0..7, b*8+hd 0..63), 512 threads (8 waves)
// Q/K from head-panels qkh[b][slot][px_ord][32] -> fully contiguous stripe
// slices for BOTH stripe orientations. V from vmt. setprio(1) around MFMA
// clusters (T5: wave role-diversity regime, +4-7% measured on attn).
__global__ __launch_bounds__(512) void k_attn(const unsigned short* __restrict__ qkh,
                                              const unsigned short* __restrict__ vmt,
                                              unsigned short* __restrict__ aout) {
  __shared__ __align__(16) unsigned short Ks[12288];  // 24 j * 4 g * 16 q granules
  __shared__ __align__(16) unsigned short Vf[12800];  // 50 Gc * 32 d granules (d swizzled)
  __shared__ __align__(16) unsigned short Pf[4096];   // 8 waves * 4 Gl * 16 q granules
  int s = blockIdx.x;
  int hd = blockIdx.y & 7, b = blockIdx.y >> 3;
  int t = threadIdx.x, lane = t & 63, wv = t >> 6;
  bool wst = (hd >= 4);
  int q = lane & 15, g = lane >> 4;
  int sbase = s * SEQ;

  const unsigned short* qh = qkh + (((size_t)b * 16 + hd) * HWn + sbase) * 32;
  const unsigned short* kh = qkh + (((size_t)b * 16 + 8 + hd) * HWn + sbase) * 32;

  // ---- Q prefetch: all per-wave Q fragments, issued first ----
  short8 qpre[4];
#pragma unroll
  for (int it = 0; it < 4; it++) {
    int qb = it * 8 + wv;
    int qi = qb * 16 + q;
    int qil = (qi < SEQ) ? qi : 391;
    qpre[it] = *(const short8*)(qh + (size_t)qil * 32 + g * 8);
  }

  // ---- stage K keys 0..383, fragment-major (contiguous 64B rows) ----
#pragma unroll
  for (int P = 0; P < 3; P++) {
    int key = P * 128 + (t >> 2);
    int gg = t & 3;
    short8 kv = *(const short8*)(kh + (size_t)key * 32 + gg * 8);
    *(short8*)&Ks[((((key >> 4) * 4 + gg) * 16) + (key & 15)) * 8] = kv;
  }
  // ---- j=24 K fragment (keys 384..391; 392+ masked later) in regs ----
  short8 kf24;
  {
    int key = 384 + q; if (key > 391) key = 391;
    kf24 = *(const short8*)(kh + (size_t)key * 32 + g * 8);
  }
  // ---- stage V fragment-major with d-swizzle ----
  const unsigned short* vg = vmt + ((size_t)(b * Cn + hd * HDIM)) * HWn + sbase;
  for (int idx = t; idx < 1600; idx += 512) {
    int d = idx / 50, Gc = idx % 50;
    short8 vv = *(const short8*)(vg + (size_t)d * HWn + Gc * 8);
    *(short8*)&Vf[(Gc * 32 + (d ^ (Gc & 7))) * 8] = vv;
  }
  __syncthreads();

  floatx4 z4 = {0.f, 0.f, 0.f, 0.f};
  unsigned short* Pw = &Pf[wv * 512];
  int gh = g >> 1, ge = (g & 1) * 4;

#pragma unroll
  for (int it = 0; it < 4; it++) {
    int qb = it * 8 + wv;
    if (qb >= 25) continue;
    int qi = qb * 16 + q;
    int qil = (qi < SEQ) ? qi : 391;
    short8 qf = qpre[it];

    // QK^T (swapped): lane holds S^T[key 4g+r][query q], in log2 units
    floatx4 sacc[25];
    __builtin_amdgcn_s_setprio(1);
#pragma unroll
    for (int j = 0; j < 24; j++) {
      short8 kf = *(const short8*)&Ks[((j * 4 + g) * 16 + q) * 8];
      sacc[j] = __builtin_amdgcn_mfma_f32_16x16x32_bf16(kf, qf, z4, 0, 0, 0);
    }
    sacc[24] = __builtin_amdgcn_mfma_f32_16x16x32_bf16(kf24, qf, z4, 0, 0, 0);
    __builtin_amdgcn_s_setprio(0);
    if (g >= 2) { sacc[24][0] = sacc[24][1] = sacc[24][2] = sacc[24][3] = -3.0e38f; }

    // softmax sans max-subtraction (scores bounded; masked -> exp2 -> 0)
    float sm = 0.f;
#pragma unroll
    for (int j = 0; j < 25; j++) {
      float e0 = EXP2(sacc[j][0]); float e1 = EXP2(sacc[j][1]);
      float e2 = EXP2(sacc[j][2]); float e3 = EXP2(sacc[j][3]);
      sacc[j][0] = e0; sacc[j][1] = e1; sacc[j][2] = e2; sacc[j][3] = e3;
      sm += (e0 + e1) + (e2 + e3);
    }
    sm += __shfl_xor(sm, 16);
    sm += __shfl_xor(sm, 32);
    float rcp = 1.0f / sm;

// jbW is clamped to stay in-bounds textually; the guard keeps semantics.
#define WRITEP(cc) do {                                                        \
    enum { jbW = (2*(cc)+1 < 25) ? (2*(cc)+1) : 24 };                          \
    uint2 wA, wB;                                                              \
    wA.x = cvt_pk_bf16(sacc[2*(cc)][0], sacc[2*(cc)][1]);                      \
    wA.y = cvt_pk_bf16(sacc[2*(cc)][2], sacc[2*(cc)][3]);                      \
    if (2*(cc)+1 < 25) {                                                       \
      wB.x = cvt_pk_bf16(sacc[jbW][0], sacc[jbW][1]);                          \
      wB.y = cvt_pk_bf16(sacc[jbW][2], sacc[jbW][3]);                          \
    } else { wB.x = 0u; wB.y = 0u; }                                           \
    *(uint2*)&Pw[(gh * 16 + q) * 8 + ge] = wA;                                 \
    *(uint2*)&Pw[((2 + gh) * 16 + q) * 8 + ge] = wB;                           \
  } while (0)

    // PV: 13 chunks of 32 keys; P round-trips per-wave LDS, pipelined 1 ahead
    floatx4 o0 = z4, o1 = z4;
    WRITEP(0);
#pragma unroll
    for (int ch = 0; ch < 13; ch++) {
      asm volatile("s_waitcnt lgkmcnt(0)" ::: "memory");
      short8 pfr = *(const short8*)&Pw[(g * 16 + q) * 8];
      int Gc = ch * 4 + g; if (Gc > 49) Gc = 49;
      int sw = Gc & 7;
      short8 vf0 = *(const short8*)&Vf[(Gc * 32 + (q ^ sw)) * 8];
      short8 vf1 = *(const short8*)&Vf[(Gc * 32 + 16 + (q ^ sw)) * 8];
      if (ch < 12) {
        switch (ch + 1) {   // keep sacc indices compile-time after unroll
          case 1: WRITEP(1); break;  case 2: WRITEP(2); break;
          case 3: WRITEP(3); break;  case 4: WRITEP(4); break;
          case 5: WRITEP(5); break;  case 6: WRITEP(6); break;
          case 7: WRITEP(7); break;  case 8: WRITEP(8); break;
          case 9: WRITEP(9); break;  case 10: WRITEP(10); break;
          case 11: WRITEP(11); break; case 12: WRITEP(12); break;
        }
      }
      __builtin_amdgcn_s_setprio(1);
      o0 = __builtin_amdgcn_mfma_f32_16x16x32_bf16(vf0, pfr, o0, 0, 0, 0);
      o1 = __builtin_amdgcn_mfma_f32_16x16x32_bf16(vf1, pfr, o1, 0, 0, 0);
      __builtin_amdgcn_s_setprio(0);
    }
#undef WRITEP

    if (qi < SEQ) {
      int pq = wst ? ((qil % Wn) * Wn + s * 7 + qil / Wn) : (sbase + qil);
      size_t ob = ((size_t)b * HWn + pq) * Cn + hd * HDIM;
      ushort4 u0, u1;
      u0.x = f2bf(o0[0] * rcp); u0.y = f2bf(o0[1] * rcp);
      u0.z = f2bf(o0[2] * rcp); u0.w = f2bf(o0[3] * rcp);
      u1.x = f2bf(o1[0] * rcp); u1.y = f2bf(o1[1] * rcp);
      u1.z = f2bf(o1[2] * rcp); u1.w = f2bf(o1[3] * rcp);
      *(ushort4*)(aout + ob + g * 4) = u0;
      *(ushort4*)(aout + ob + 16 + g * 4) = u1;
    }
  }
}

extern "C" void kernel_launch(void* const* d_in, const int* in_sizes, int n_in,
                              void* d_out, int out_size, void* d_ws, size_t ws_size,
                              hipStream_t stream) {
  const float* x     = (const float*)d_in[0];
  const float* wqkv  = (const float*)d_in[1];
  const float* bqkv  = (const float*)d_in[2];
  const float* wdw   = (const float*)d_in[3];
  const float* bdw   = (const float*)d_in[4];
  const float* wproj = (const float*)d_in[5];
  const float* bproj = (const float*)d_in[6];
  float* out = (float*)d_out;

  unsigned short* xt   = (unsigned short*)d_ws;                    // [B][HW][256] bf16
  unsigned short* wqb  = xt + (size_t)Bn * HWn * Cn;               // [768][256]
  unsigned short* wpb  = wqb + 768 * 256;                          // [256][256]
  unsigned short* qkh  = wpb + 256 * 256;                          // [B][16][HW][32] head-panels
  unsigned short* vb   = qkh + (size_t)Bn * 16 * HWn * 32;         // [B][HW][256] v pixel-major
  unsigned short* vmt  = vb + (size_t)Bn * HWn * Cn;               // [B][256ch][HW]
  unsigned short* aout = vmt + (size_t)Bn * HWn * Cn;              // [B][HW][256]

  k_prep<<<dim3(256 + 98 * 8 * Bn), 256, 0, stream>>>(wqkv, wproj, wqb, wpb, x, xt);
  k_gemm<0><<<dim3(1200), 512, 0, stream>>>(wqb, xt, bqkv, qkh, nullptr, vb, 768, HWn, 6, 150);
  k_dwconv_t<<<dim3(196, 2, Bn), 256, 0, stream>>>(vb, wdw, bdw, vmt);
  k_attn<<<dim3(NSTR, Bn * NHEADS), 512, 0, stream>>>(qkh, vmt, aout);
  k_gemm<1><<<dim3(400), 512, 0, stream>>>(wpb, aout, bproj, nullptr, out, nullptr, 256, HWn, 2, 50);
}

// Round 16
// 105.006 us; speedup vs baseline: 1.7734x; 1.0055x over previous
//
#include <hip/hip_runtime.h>
#include <hip/hip_bf16.h>
#include <stdint.h>

#define Bn 8
#define Cn 256
#define Hn 56
#define Wn 56
#define HWn 3136
#define NHEADS 8
#define HDIM 32
#define SEQ 392
#define NSTR 8
#define QKV_LD 768
// SCALE * log2(e): K is pre-scaled by this in the qkv-GEMM epilogue so the
// attention softmax can use exp2 with no per-score multiply.
#define KSC (0.17677669529663689f * 1.4426950408889634f)

#if __has_builtin(__builtin_amdgcn_exp2f)
#define EXP2(x) __builtin_amdgcn_exp2f(x)
#else
#define EXP2(x) exp2f(x)
#endif

typedef short short8 __attribute__((ext_vector_type(8)));
typedef float floatx4 __attribute__((ext_vector_type(4)));

__device__ __forceinline__ unsigned short f2bf(float f) {
  union { float f; uint32_t u; } v; v.f = f;
  uint32_t u = v.u;
  u += 0x7fffu + ((u >> 16) & 1u);   // RNE
  return (unsigned short)(u >> 16);
}
__device__ __forceinline__ float bf2f(unsigned short h) {
  union { uint32_t u; float f; } v; v.u = ((uint32_t)h) << 16;
  return v.f;
}
__device__ __forceinline__ uint32_t cvt_pk_bf16(float lo, float hi) {
  uint32_t r;
  asm("v_cvt_pk_bf16_f32 %0, %1, %2" : "=v"(r) : "v"(lo), "v"(hi));
  return r;
}
// async global->LDS, 16B per lane; LDS dest = wave-uniform base + lane*16
__device__ __forceinline__ void gload16(const unsigned short* g, unsigned short* l) {
  __builtin_amdgcn_global_load_lds((const __attribute__((address_space(1))) void*)g,
                                   (__attribute__((address_space(3))) void*)l, 16, 0, 0);
}

// ---------------- prep: weight cvt (blocks 0..255) + x transpose (blocks 256+) ----------------
__global__ __launch_bounds__(256) void k_prep(const float* __restrict__ wa,
                                              const float* __restrict__ wb,
                                              unsigned short* __restrict__ da,
                                              unsigned short* __restrict__ db,
                                              const float* __restrict__ x,
                                              unsigned short* __restrict__ xt) {
  int bx = blockIdx.x;
  int t = threadIdx.x;
  if (bx < 256) {
    int i = bx * 256 + t;   // 65536 float4 slots total
    if (i < 49152) {
      float4 v = ((const float4*)wa)[i];
      ushort4 o;
      o.x = f2bf(v.x); o.y = f2bf(v.y); o.z = f2bf(v.z); o.w = f2bf(v.w);
      ((ushort4*)da)[i] = o;
    } else {
      int k = i - 49152;
      float4 v = ((const float4*)wb)[k];
      ushort4 o;
      o.x = f2bf(v.x); o.y = f2bf(v.y); o.z = f2bf(v.z); o.w = f2bf(v.w);
      ((ushort4*)db)[k] = o;
    }
    return;
  }
  __shared__ float tile[32][33];
  int tx = bx - 256;
  int pb = tx % 98, cb = (tx / 98) & 7, b = tx / 784;
  int c = t >> 3, p4 = (t & 7) * 4;
  float4 v = *(const float4*)(x + (((size_t)b * Cn + cb * 32 + c) * HWn + pb * 32 + p4));
  tile[c][p4 + 0] = v.x; tile[c][p4 + 1] = v.y; tile[c][p4 + 2] = v.z; tile[c][p4 + 3] = v.w;
  __syncthreads();
  int p = t >> 3, c4 = (t & 7) * 4;
  ushort4 o;
  o.x = f2bf(tile[c4 + 0][p]); o.y = f2bf(tile[c4 + 1][p]);
  o.z = f2bf(tile[c4 + 2][p]); o.w = f2bf(tile[c4 + 3][p]);
  *(ushort4*)(xt + (((size_t)b * HWn + pb * 32 + p) * Cn + cb * 32 + c4)) = o;
}

// ---------------- qkv GEMM (M=768, K=256, BK=32): 32 KB LDS -> 4 blocks/CU ----------------
// 512 threads (8 waves), depth-2 counted-vmcnt(2) over 8 K-tiles, n-major tile
// order + XCD batch chunking, swizzle slot^=(row&3) src-side / g^(q&3) read-side.
// Epilogue: m-tiles 0-3 (q,k) -> qkh[b][slot][px_ord][32] (K pre-scaled KSC);
// m-tiles 4-5 (v) -> outV[b][px][256]. Plain stores (NT = 4x write amp, R11).
__global__ __launch_bounds__(512) void k_gemm0(const unsigned short* __restrict__ A,
                                               const unsigned short* __restrict__ Bt,
                                               const float* __restrict__ bias,
                                               unsigned short* __restrict__ qkh,
                                               unsigned short* __restrict__ outV) {
  const int K = 256, N = HWn;
  __shared__ __align__(16) unsigned short SH[16384];   // As[2][4096] + Bs[2][4096]
  unsigned short* As = SH;
  unsigned short* Bs = SH + 8192;
  int t = threadIdx.x;
  int raw = blockIdx.x;
  int chunk = gridDim.x >> 3;
  int wg = (raw & 7) * chunk + (raw >> 3);     // bijective (grid % 8 == 0)
  int b = wg / 150, r = wg % 150;
  int m0 = (r % 6) * 128, n0 = (r / 6) * 128;
  const unsigned short* Bb = Bt + (size_t)b * N * K;
  int lane = t & 63, w = t >> 6;
  int wr = w >> 1, wc = w & 1;
  int g = lane >> 4, q = lane & 15;
  int rt = t >> 2, st = t & 3;                 // staging row / slot
  int cs = st ^ (rt & 3);
  const unsigned short* Ag = A + (size_t)(m0 + rt) * K + cs * 8;
  int nr = n0 + rt;
  const unsigned short* Bg = Bb + (size_t)((nr < N) ? nr : (N - 1)) * K + cs * 8;
  int ldst = t * 8;

  floatx4 z4 = {0.f, 0.f, 0.f, 0.f};
  floatx4 acc[2][4];
#pragma unroll
  for (int i = 0; i < 2; i++)
#pragma unroll
    for (int j = 0; j < 4; j++) acc[i][j] = z4;

#define STAGE0(kt, off) do {                                                   \
    gload16(Ag + (kt) * 32, &As[(off) + ldst]);                                \
    gload16(Bg + (kt) * 32, &Bs[(off) + ldst]);                                \
  } while (0)

#define COMPUTE0(off) do {                                                     \
    short8 af[2], bfr[4];                                                      \
    _Pragma("unroll")                                                          \
    for (int i = 0; i < 2; i++) {                                              \
      int row = wr * 32 + i * 16 + q;                                          \
      af[i] = *(const short8*)&As[(off) + row * 32 + ((g ^ (q & 3)) << 3)];    \
    }                                                                          \
    _Pragma("unroll")                                                          \
    for (int j = 0; j < 4; j++) {                                              \
      int row = wc * 64 + j * 16 + q;                                          \
      bfr[j] = *(const short8*)&Bs[(off) + row * 32 + ((g ^ (q & 3)) << 3)];   \
    }                                                                          \
    _Pragma("unroll")                                                          \
    for (int i = 0; i < 2; i++)                                                \
      _Pragma("unroll")                                                        \
      for (int j = 0; j < 4; j++)                                              \
        acc[i][j] = __builtin_amdgcn_mfma_f32_16x16x32_bf16(af[i], bfr[j], acc[i][j], 0, 0, 0); \
  } while (0)

  STAGE0(0, 0);
  STAGE0(1, 4096);
#pragma unroll
  for (int tt = 0; tt < 8; tt++) {
    if (tt < 7) { asm volatile("s_waitcnt vmcnt(2)" ::: "memory"); }
    else       { asm volatile("s_waitcnt vmcnt(0)" ::: "memory"); }
    __syncthreads();
    COMPUTE0((tt & 1) * 4096);
    __syncthreads();
    if (tt < 6) STAGE0(tt + 2, (tt & 1) * 4096);
  }
#undef STAGE0
#undef COMPUTE0

  // ---- LDS-transposed epilogue: E[col 128][16 granules x 8ch], XOR-swizzled ----
  unsigned short* E = SH;   // 32768 B, exactly fits
#pragma unroll
  for (int i = 0; i < 2; i++) {
    int ob = m0 + wr * 32 + i * 16 + g * 4;
    float bs0 = bias[ob + 0], bs1 = bias[ob + 1], bs2 = bias[ob + 2], bs3 = bias[ob + 3];
    float sc = (ob >= 256 && ob < 512) ? KSC : 1.0f;
    int lobg = wr * 4 + i * 2 + (g >> 1);
#pragma unroll
    for (int j = 0; j < 4; j++) {
      int lc = wc * 64 + j * 16 + q;
      ushort4 o;
      o.x = f2bf((acc[i][j][0] + bs0) * sc);
      o.y = f2bf((acc[i][j][1] + bs1) * sc);
      o.z = f2bf((acc[i][j][2] + bs2) * sc);
      o.w = f2bf((acc[i][j][3] + bs3) * sc);
      *(ushort4*)&E[lc * 128 + ((lobg ^ (lc & 7)) << 3) + (g & 1) * 4] = o;
    }
  }
  __syncthreads();
  int c = t >> 2, part = t & 3;
  int col = n0 + c;
  if (col < N) {
    int mt = m0 >> 7;            // 0..5
    unsigned short* dst;
    if (mt < 4) {                // q,k head-panels
      int hd = (mt & 1) * 4 + part;
      int sl = (mt >> 1) * 8 + hd;           // isK*8 + head
      int p_ord = (hd >= 4) ? ((col % Wn) * Wn + col / Wn) : col;
      dst = qkh + (((size_t)b * 16 + sl) * HWn + p_ord) * 32;
    } else {                     // v pixel-major
      dst = outV + ((size_t)b * HWn + col) * 256 + (m0 - 512) + part * 32;
    }
#pragma unroll
    for (int k2 = part * 4; k2 < part * 4 + 4; k2++) {   // 32 chans = 64B contiguous
      short8 v = *(const short8*)&E[c * 128 + ((k2 ^ (c & 7)) << 3)];
      *(short8*)(dst + (k2 - part * 4) * 8) = v;
    }
  }
}

// ---------------- proj GEMM (M=256, K=256, BK=64) - unchanged R15 structure ----------------
__global__ __launch_bounds__(512) void k_gemm1(const unsigned short* __restrict__ A,
                                               const unsigned short* __restrict__ Bt,
                                               const float* __restrict__ bias,
                                               float* __restrict__ outF,
                                               int M, int N, int nm, int nper) {
  const int K = 256;
  __shared__ __align__(16) char SH[67584];
  unsigned short* As = (unsigned short*)SH;   // [2][8192]
  unsigned short* Bs = As + 16384;            // [2][8192]
  int t = threadIdx.x;
  int raw = blockIdx.x;
  int chunk = gridDim.x >> 3;
  int wg = (raw & 7) * chunk + (raw >> 3);
  int b = wg / nper, r = wg % nper;
  int m0 = (r % nm) * 128, n0 = (r / nm) * 128;
  const unsigned short* Bb = Bt + (size_t)b * N * K;
  int lane = t & 63, w = t >> 6;
  int wr = w >> 1, wc = w & 1;
  int g = lane >> 4, q = lane & 15;
  int srow8 = lane >> 3;
  int slot = lane & 7;

  const unsigned short* Ag[2];
  const unsigned short* Bg[2];
  int ldst[2];
#pragma unroll
  for (int i = 0; i < 2; i++) {
    int row = i * 64 + w * 8 + srow8;
    int cs = slot ^ srow8;
    Ag[i] = A + (size_t)(m0 + row) * K + cs * 8;
    int nr = n0 + row;
    Bg[i] = Bb + (size_t)((nr < N) ? nr : (N - 1)) * K + cs * 8;
    ldst[i] = (i * 64 + w * 8) * 64;
  }

  floatx4 z4 = {0.f, 0.f, 0.f, 0.f};
  floatx4 acc[2][4];
#pragma unroll
  for (int i = 0; i < 2; i++)
#pragma unroll
    for (int j = 0; j < 4; j++) acc[i][j] = z4;

#define STAGE(kt, off) do {                                                    \
    _Pragma("unroll")                                                          \
    for (int i = 0; i < 2; i++) gload16(Ag[i] + (kt) * 64, &As[(off) + ldst[i]]); \
    _Pragma("unroll")                                                          \
    for (int i = 0; i < 2; i++) gload16(Bg[i] + (kt) * 64, &Bs[(off) + ldst[i]]); \
  } while (0)

#define COMPUTE(off) do {                                                      \
    _Pragma("unroll")                                                          \
    for (int kk = 0; kk < 64; kk += 32) {                                      \
      short8 af[2], bfr[4];                                                    \
      _Pragma("unroll")                                                        \
      for (int i = 0; i < 2; i++) {                                            \
        int row = wr * 32 + i * 16 + q;                                        \
        af[i] = *(const short8*)&As[(off) + row * 64 + ((((kk >> 3) + g) ^ (q & 7)) << 3)]; \
      }                                                                        \
      _Pragma("unroll")                                                        \
      for (int j = 0; j < 4; j++) {                                            \
        int row = wc * 64 + j * 16 + q;                                        \
        bfr[j] = *(const short8*)&Bs[(off) + row * 64 + ((((kk >> 3) + g) ^ (q & 7)) << 3)]; \
      }                                                                        \
      _Pragma("unroll")                                                        \
      for (int i = 0; i < 2; i++)                                              \
        _Pragma("unroll")                                                      \
        for (int j = 0; j < 4; j++)                                            \
          acc[i][j] = __builtin_amdgcn_mfma_f32_16x16x32_bf16(af[i], bfr[j], acc[i][j], 0, 0, 0); \
    }                                                                          \
  } while (0)

  STAGE(0, 0);
  STAGE(1, 8192);
  asm volatile("s_waitcnt vmcnt(4)" ::: "memory");
  __syncthreads();
  COMPUTE(0);
  __syncthreads();
  STAGE(2, 0);
  asm volatile("s_waitcnt vmcnt(4)" ::: "memory");
  __syncthreads();
  COMPUTE(8192);
  __syncthreads();
  STAGE(3, 8192);
  asm volatile("s_waitcnt vmcnt(4)" ::: "memory");
  __syncthreads();
  COMPUTE(0);
  asm volatile("s_waitcnt vmcnt(0)" ::: "memory");
  __syncthreads();
  COMPUTE(8192);
#undef STAGE
#undef COMPUTE

  __syncthreads();
  float* Ef = (float*)SH;   // [row 128][132]
#pragma unroll
  for (int i = 0; i < 2; i++) {
    int ob = m0 + wr * 32 + i * 16 + g * 4;
    int lob = wr * 32 + i * 16 + g * 4;
    float bs0 = bias[ob + 0], bs1 = bias[ob + 1], bs2 = bias[ob + 2], bs3 = bias[ob + 3];
#pragma unroll
    for (int j = 0; j < 4; j++) {
      int lc = wc * 64 + j * 16 + q;
      Ef[(lob + 0) * 132 + lc] = acc[i][j][0] + bs0;
      Ef[(lob + 1) * 132 + lc] = acc[i][j][1] + bs1;
      Ef[(lob + 2) * 132 + lc] = acc[i][j][2] + bs2;
      Ef[(lob + 3) * 132 + lc] = acc[i][j][3] + bs3;
    }
  }
  __syncthreads();
  int rr = t >> 2, seg = t & 3;
  float* dst = outF + (size_t)b * M * N + (size_t)(m0 + rr) * N + n0;
#pragma unroll
  for (int k2 = 0; k2 < 8; k2++) {
    int col = seg * 32 + k2 * 4;
    if (n0 + col < N) {
      floatx4 v = *(const floatx4*)&Ef[rr * 132 + col];
      *(floatx4*)(dst + col) = v;
    }
  }
}

// ---------------- depthwise 3x3 on v (vb[b][px][256]), output vmt[b][ch][pixel] ----------------
// 512 threads, 32 px/block -> 64B contiguous vmt writes per channel (full sectors).
// pass 0: heads 0..3, h-major pixel order; pass 1: heads 4..7, w-major order.
__global__ __launch_bounds__(512) void k_dwconv_t(const unsigned short* __restrict__ vb,
                                                  const float* __restrict__ wdw,
                                                  const float* __restrict__ bdw,
                                                  unsigned short* __restrict__ vmt) {
  __shared__ float wS[1152];
  __shared__ float bS[128];
  __shared__ __align__(16) unsigned short tile[32][140];
  int t = threadIdx.x;
  int pass = blockIdx.y, b = blockIdx.z;
  for (int i = t; i < 1152; i += 512) wS[i] = wdw[pass * 1152 + i];
  if (t < 128) bS[t] = bdw[pass * 128 + t];
  __syncthreads();

  int pi = t >> 4, c8 = (t & 15) * 8;
  int i32 = blockIdx.x * 32 + pi;
  int h, w;
  if (pass == 0) { h = i32 / Wn; w = i32 % Wn; }
  else           { w = i32 / Hn; h = i32 % Hn; }

  const unsigned short* vq = vb + pass * 128 + c8;
  float a[8];
  short8 vc = *(const short8*)(vq + ((size_t)b * HWn + h * Wn + w) * 256);
#pragma unroll
  for (int e = 0; e < 8; e++) a[e] = bf2f((unsigned short)vc[e]) + bS[c8 + e];
#pragma unroll
  for (int ky = 0; ky < 3; ky++) {
    int hh = h + ky - 1;
    if (hh < 0 || hh >= Hn) continue;
#pragma unroll
    for (int kx = 0; kx < 3; kx++) {
      int ww = w + kx - 1;
      if (ww < 0 || ww >= Wn) continue;
      short8 vn = *(const short8*)(vq + ((size_t)b * HWn + hh * Wn + ww) * 256);
#pragma unroll
      for (int e = 0; e < 8; e++) a[e] += bf2f((unsigned short)vn[e]) * wS[(c8 + e) * 9 + ky * 3 + kx];
    }
  }
  short8 o;
#pragma unroll
  for (int e = 0; e < 8; e++) o[e] = (short)f2bf(a[e]);
  *(short8*)&tile[pi][c8] = o;
  __syncthreads();

  int dd = t >> 2, quarter = t & 3;
  short8 ov;
#pragma unroll
  for (int k2 = 0; k2 < 8; k2++) ov[k2] = (short)tile[quarter * 8 + k2][dd];
  *(short8*)(vmt + ((size_t)(b * Cn + pass * 128 + dd)) * HWn + blockIdx.x * 32 + quarter * 8) = ov;
}

// ---------------- stripe attention ----------------
// grid: (stripe 0..7, b*8+hd 0..63), 512 threads (8 waves)
// Q/K from head-panels qkh[b][slot][px_ord][32] -> fully contiguous stripe
// slices for BOTH stripe orientations. V from vmt. setprio(1) around MFMA
// clusters (T5: wave role-diversity regime, +4-7% measured on attn).
__global__ __launch_bounds__(512) void k_attn(const unsigned short* __restrict__ qkh,
                                              const unsigned short* __restrict__ vmt,
                                              unsigned short* __restrict__ aout) {
  __shared__ __align__(16) unsigned short Ks[12288];  // 24 j * 4 g * 16 q granules
  __shared__ __align__(16) unsigned short Vf[12800];  // 50 Gc * 32 d granules (d swizzled)
  __shared__ __align__(16) unsigned short Pf[4096];   // 8 waves * 4 Gl * 16 q granules
  int s = blockIdx.x;
  int hd = blockIdx.y & 7, b = blockIdx.y >> 3;
  int t = threadIdx.x, lane = t & 63, wv = t >> 6;
  bool wst = (hd >= 4);
  int q = lane & 15, g = lane >> 4;
  int sbase = s * SEQ;

  const unsigned short* qh = qkh + (((size_t)b * 16 + hd) * HWn + sbase) * 32;
  const unsigned short* kh = qkh + (((size_t)b * 16 + 8 + hd) * HWn + sbase) * 32;

  // ---- Q prefetch: all per-wave Q fragments, issued first ----
  short8 qpre[4];
#pragma unroll
  for (int it = 0; it < 4; it++) {
    int qb = it * 8 + wv;
    int qi = qb * 16 + q;
    int qil = (qi < SEQ) ? qi : 391;
    qpre[it] = *(const short8*)(qh + (size_t)qil * 32 + g * 8);
  }

  // ---- stage K keys 0..383, fragment-major (contiguous 64B rows) ----
#pragma unroll
  for (int P = 0; P < 3; P++) {
    int key = P * 128 + (t >> 2);
    int gg = t & 3;
    short8 kv = *(const short8*)(kh + (size_t)key * 32 + gg * 8);
    *(short8*)&Ks[((((key >> 4) * 4 + gg) * 16) + (key & 15)) * 8] = kv;
  }
  // ---- j=24 K fragment (keys 384..391; 392+ masked later) in regs ----
  short8 kf24;
  {
    int key = 384 + q; if (key > 391) key = 391;
    kf24 = *(const short8*)(kh + (size_t)key * 32 + g * 8);
  }
  // ---- stage V fragment-major with d-swizzle ----
  const unsigned short* vg = vmt + ((size_t)(b * Cn + hd * HDIM)) * HWn + sbase;
  for (int idx = t; idx < 1600; idx += 512) {
    int d = idx / 50, Gc = idx % 50;
    short8 vv = *(const short8*)(vg + (size_t)d * HWn + Gc * 8);
    *(short8*)&Vf[(Gc * 32 + (d ^ (Gc & 7))) * 8] = vv;
  }
  __syncthreads();

  floatx4 z4 = {0.f, 0.f, 0.f, 0.f};
  unsigned short* Pw = &Pf[wv * 512];
  int gh = g >> 1, ge = (g & 1) * 4;

#pragma unroll
  for (int it = 0; it < 4; it++) {
    int qb = it * 8 + wv;
    if (qb >= 25) continue;
    int qi = qb * 16 + q;
    int qil = (qi < SEQ) ? qi : 391;
    short8 qf = qpre[it];

    // QK^T (swapped): lane holds S^T[key 4g+r][query q], in log2 units
    floatx4 sacc[25];
    __builtin_amdgcn_s_setprio(1);
#pragma unroll
    for (int j = 0; j < 24; j++) {
      short8 kf = *(const short8*)&Ks[((j * 4 + g) * 16 + q) * 8];
      sacc[j] = __builtin_amdgcn_mfma_f32_16x16x32_bf16(kf, qf, z4, 0, 0, 0);
    }
    sacc[24] = __builtin_amdgcn_mfma_f32_16x16x32_bf16(kf24, qf, z4, 0, 0, 0);
    __builtin_amdgcn_s_setprio(0);
    if (g >= 2) { sacc[24][0] = sacc[24][1] = sacc[24][2] = sacc[24][3] = -3.0e38f; }

    // softmax sans max-subtraction (scores bounded; masked -> exp2 -> 0)
    float sm = 0.f;
#pragma unroll
    for (int j = 0; j < 25; j++) {
      float e0 = EXP2(sacc[j][0]); float e1 = EXP2(sacc[j][1]);
      float e2 = EXP2(sacc[j][2]); float e3 = EXP2(sacc[j][3]);
      sacc[j][0] = e0; sacc[j][1] = e1; sacc[j][2] = e2; sacc[j][3] = e3;
      sm += (e0 + e1) + (e2 + e3);
    }
    sm += __shfl_xor(sm, 16);
    sm += __shfl_xor(sm, 32);
    float rcp = 1.0f / sm;

// jbW is clamped to stay in-bounds textually; the guard keeps semantics.
#define WRITEP(cc) do {                                                        \
    enum { jbW = (2*(cc)+1 < 25) ? (2*(cc)+1) : 24 };                          \
    uint2 wA, wB;                                                              \
    wA.x = cvt_pk_bf16(sacc[2*(cc)][0], sacc[2*(cc)][1]);                      \
    wA.y = cvt_pk_bf16(sacc[2*(cc)][2], sacc[2*(cc)][3]);                      \
    if (2*(cc)+1 < 25) {                                                       \
      wB.x = cvt_pk_bf16(sacc[jbW][0], sacc[jbW][1]);                          \
      wB.y = cvt_pk_bf16(sacc[jbW][2], sacc[jbW][3]);                          \
    } else { wB.x = 0u; wB.y = 0u; }                                           \
    *(uint2*)&Pw[(gh * 16 + q) * 8 + ge] = wA;                                 \
    *(uint2*)&Pw[((2 + gh) * 16 + q) * 8 + ge] = wB;                           \
  } while (0)

    // PV: 13 chunks of 32 keys; P round-trips per-wave LDS, pipelined 1 ahead
    floatx4 o0 = z4, o1 = z4;
    WRITEP(0);
#pragma unroll
    for (int ch = 0; ch < 13; ch++) {
      asm volatile("s_waitcnt lgkmcnt(0)" ::: "memory");
      short8 pfr = *(const short8*)&Pw[(g * 16 + q) * 8];
      int Gc = ch * 4 + g; if (Gc > 49) Gc = 49;
      int sw = Gc & 7;
      short8 vf0 = *(const short8*)&Vf[(Gc * 32 + (q ^ sw)) * 8];
      short8 vf1 = *(const short8*)&Vf[(Gc * 32 + 16 + (q ^ sw)) * 8];
      if (ch < 12) {
        switch (ch + 1) {   // keep sacc indices compile-time after unroll
          case 1: WRITEP(1); break;  case 2: WRITEP(2); break;
          case 3: WRITEP(3); break;  case 4: WRITEP(4); break;
          case 5: WRITEP(5); break;  case 6: WRITEP(6); break;
          case 7: WRITEP(7); break;  case 8: WRITEP(8); break;
          case 9: WRITEP(9); break;  case 10: WRITEP(10); break;
          case 11: WRITEP(11); break; case 12: WRITEP(12); break;
        }
      }
      __builtin_amdgcn_s_setprio(1);
      o0 = __builtin_amdgcn_mfma_f32_16x16x32_bf16(vf0, pfr, o0, 0, 0, 0);
      o1 = __builtin_amdgcn_mfma_f32_16x16x32_bf16(vf1, pfr, o1, 0, 0, 0);
      __builtin_amdgcn_s_setprio(0);
    }
#undef WRITEP

    if (qi < SEQ) {
      int pq = wst ? ((qil % Wn) * Wn + s * 7 + qil / Wn) : (sbase + qil);
      size_t ob = ((size_t)b * HWn + pq) * Cn + hd * HDIM;
      ushort4 u0, u1;
      u0.x = f2bf(o0[0] * rcp); u0.y = f2bf(o0[1] * rcp);
      u0.z = f2bf(o0[2] * rcp); u0.w = f2bf(o0[3] * rcp);
      u1.x = f2bf(o1[0] * rcp); u1.y = f2bf(o1[1] * rcp);
      u1.z = f2bf(o1[2] * rcp); u1.w = f2bf(o1[3] * rcp);
      *(ushort4*)(aout + ob + g * 4) = u0;
      *(ushort4*)(aout + ob + 16 + g * 4) = u1;
    }
  }
}

extern "C" void kernel_launch(void* const* d_in, const int* in_sizes, int n_in,
                              void* d_out, int out_size, void* d_ws, size_t ws_size,
                              hipStream_t stream) {
  const float* x     = (const float*)d_in[0];
  const float* wqkv  = (const float*)d_in[1];
  const float* bqkv  = (const float*)d_in[2];
  const float* wdw   = (const float*)d_in[3];
  const float* bdw   = (const float*)d_in[4];
  const float* wproj = (const float*)d_in[5];
  const float* bproj = (const float*)d_in[6];
  float* out = (float*)d_out;

  unsigned short* xt   = (unsigned short*)d_ws;                    // [B][HW][256] bf16
  unsigned short* wqb  = xt + (size_t)Bn * HWn * Cn;               // [768][256]
  unsigned short* wpb  = wqb + 768 * 256;                          // [256][256]
  unsigned short* qkh  = wpb + 256 * 256;                          // [B][16][HW][32] head-panels
  unsigned short* vb   = qkh + (size_t)Bn * 16 * HWn * 32;         // [B][HW][256] v pixel-major
  unsigned short* vmt  = vb + (size_t)Bn * HWn * Cn;               // [B][256ch][HW]
  unsigned short* aout = vmt + (size_t)Bn * HWn * Cn;              // [B][HW][256]

  k_prep<<<dim3(256 + 98 * 8 * Bn), 256, 0, stream>>>(wqkv, wproj, wqb, wpb, x, xt);
  k_gemm0<<<dim3(1200), 512, 0, stream>>>(wqb, xt, bqkv, qkh, vb);
  k_dwconv_t<<<dim3(98, 2, Bn), 512, 0, stream>>>(vb, wdw, bdw, vmt);
  k_attn<<<dim3(NSTR, Bn * NHEADS), 512, 0, stream>>>(qkh, vmt, aout);
  k_gemm1<<<dim3(400), 512, 0, stream>>>(wpb, aout, bproj, out, 256, HWn, 2, 50);
}

// Round 17
// 102.434 us; speedup vs baseline: 1.8179x; 1.0251x over previous
//
#include <hip/hip_runtime.h>
#include <hip/hip_bf16.h>
#include <stdint.h>

#define Bn 8
#define Cn 256
#define Hn 56
#define Wn 56
#define HWn 3136
#define NHEADS 8
#define HDIM 32
#define SEQ 392
#define NSTR 8
#define QKV_LD 768
// SCALE * log2(e): K is pre-scaled by this in the qkv-GEMM epilogue so the
// attention softmax can use exp2 with no per-score multiply.
#define KSC (0.17677669529663689f * 1.4426950408889634f)

#if __has_builtin(__builtin_amdgcn_exp2f)
#define EXP2(x) __builtin_amdgcn_exp2f(x)
#else
#define EXP2(x) exp2f(x)
#endif

typedef short short8 __attribute__((ext_vector_type(8)));
typedef float floatx4 __attribute__((ext_vector_type(4)));

__device__ __forceinline__ unsigned short f2bf(float f) {
  union { float f; uint32_t u; } v; v.f = f;
  uint32_t u = v.u;
  u += 0x7fffu + ((u >> 16) & 1u);   // RNE
  return (unsigned short)(u >> 16);
}
__device__ __forceinline__ float bf2f(unsigned short h) {
  union { uint32_t u; float f; } v; v.u = ((uint32_t)h) << 16;
  return v.f;
}
__device__ __forceinline__ uint32_t cvt_pk_bf16(float lo, float hi) {
  uint32_t r;
  asm("v_cvt_pk_bf16_f32 %0, %1, %2" : "=v"(r) : "v"(lo), "v"(hi));
  return r;
}
// async global->LDS, 16B per lane; LDS dest = wave-uniform base + lane*16
__device__ __forceinline__ void gload16(const unsigned short* g, unsigned short* l) {
  __builtin_amdgcn_global_load_lds((const __attribute__((address_space(1))) void*)g,
                                   (__attribute__((address_space(3))) void*)l, 16, 0, 0);
}

// ---------------- prep: weight cvt (blocks 0..255) + x transpose (blocks 256+) ----------------
__global__ __launch_bounds__(256) void k_prep(const float* __restrict__ wa,
                                              const float* __restrict__ wb,
                                              unsigned short* __restrict__ da,
                                              unsigned short* __restrict__ db,
                                              const float* __restrict__ x,
                                              unsigned short* __restrict__ xt) {
  int bx = blockIdx.x;
  int t = threadIdx.x;
  if (bx < 256) {
    int i = bx * 256 + t;   // 65536 float4 slots total
    if (i < 49152) {
      float4 v = ((const float4*)wa)[i];
      ushort4 o;
      o.x = f2bf(v.x); o.y = f2bf(v.y); o.z = f2bf(v.z); o.w = f2bf(v.w);
      ((ushort4*)da)[i] = o;
    } else {
      int k = i - 49152;
      float4 v = ((const float4*)wb)[k];
      ushort4 o;
      o.x = f2bf(v.x); o.y = f2bf(v.y); o.z = f2bf(v.z); o.w = f2bf(v.w);
      ((ushort4*)db)[k] = o;
    }
    return;
  }
  __shared__ float tile[32][33];
  int tx = bx - 256;
  int pb = tx % 98, cb = (tx / 98) & 7, b = tx / 784;
  int c = t >> 3, p4 = (t & 7) * 4;
  float4 v = *(const float4*)(x + (((size_t)b * Cn + cb * 32 + c) * HWn + pb * 32 + p4));
  tile[c][p4 + 0] = v.x; tile[c][p4 + 1] = v.y; tile[c][p4 + 2] = v.z; tile[c][p4 + 3] = v.w;
  __syncthreads();
  int p = t >> 3, c4 = (t & 7) * 4;
  ushort4 o;
  o.x = f2bf(tile[c4 + 0][p]); o.y = f2bf(tile[c4 + 1][p]);
  o.z = f2bf(tile[c4 + 2][p]); o.w = f2bf(tile[c4 + 3][p]);
  *(ushort4*)(xt + (((size_t)b * HWn + pb * 32 + p) * Cn + cb * 32 + c4)) = o;
}

// ---------------- qkv GEMM (M=768, K=256, BK=32): 32 KB LDS ----------------
__global__ __launch_bounds__(512) void k_gemm0(const unsigned short* __restrict__ A,
                                               const unsigned short* __restrict__ Bt,
                                               const float* __restrict__ bias,
                                               unsigned short* __restrict__ qkh,
                                               unsigned short* __restrict__ outV) {
  const int K = 256, N = HWn;
  __shared__ __align__(16) unsigned short SH[16384];   // As[2][4096] + Bs[2][4096]
  unsigned short* As = SH;
  unsigned short* Bs = SH + 8192;
  int t = threadIdx.x;
  int raw = blockIdx.x;
  int chunk = gridDim.x >> 3;
  int wg = (raw & 7) * chunk + (raw >> 3);     // bijective (grid % 8 == 0)
  int b = wg / 150, r = wg % 150;
  int m0 = (r % 6) * 128, n0 = (r / 6) * 128;
  const unsigned short* Bb = Bt + (size_t)b * N * K;
  int lane = t & 63, w = t >> 6;
  int wr = w >> 1, wc = w & 1;
  int g = lane >> 4, q = lane & 15;
  int rt = t >> 2, st = t & 3;                 // staging row / slot
  int cs = st ^ (rt & 3);
  const unsigned short* Ag = A + (size_t)(m0 + rt) * K + cs * 8;
  int nr = n0 + rt;
  const unsigned short* Bg = Bb + (size_t)((nr < N) ? nr : (N - 1)) * K + cs * 8;
  int ldst = t * 8;

  floatx4 z4 = {0.f, 0.f, 0.f, 0.f};
  floatx4 acc[2][4];
#pragma unroll
  for (int i = 0; i < 2; i++)
#pragma unroll
    for (int j = 0; j < 4; j++) acc[i][j] = z4;

#define STAGE0(kt, off) do {                                                   \
    gload16(Ag + (kt) * 32, &As[(off) + ldst]);                                \
    gload16(Bg + (kt) * 32, &Bs[(off) + ldst]);                                \
  } while (0)

#define COMPUTE0(off) do {                                                     \
    short8 af[2], bfr[4];                                                      \
    _Pragma("unroll")                                                          \
    for (int i = 0; i < 2; i++) {                                              \
      int row = wr * 32 + i * 16 + q;                                          \
      af[i] = *(const short8*)&As[(off) + row * 32 + ((g ^ (q & 3)) << 3)];    \
    }                                                                          \
    _Pragma("unroll")                                                          \
    for (int j = 0; j < 4; j++) {                                              \
      int row = wc * 64 + j * 16 + q;                                          \
      bfr[j] = *(const short8*)&Bs[(off) + row * 32 + ((g ^ (q & 3)) << 3)];   \
    }                                                                          \
    _Pragma("unroll")                                                          \
    for (int i = 0; i < 2; i++)                                                \
      _Pragma("unroll")                                                        \
      for (int j = 0; j < 4; j++)                                              \
        acc[i][j] = __builtin_amdgcn_mfma_f32_16x16x32_bf16(af[i], bfr[j], acc[i][j], 0, 0, 0); \
  } while (0)

  STAGE0(0, 0);
  STAGE0(1, 4096);
#pragma unroll
  for (int tt = 0; tt < 8; tt++) {
    if (tt < 7) { asm volatile("s_waitcnt vmcnt(2)" ::: "memory"); }
    else       { asm volatile("s_waitcnt vmcnt(0)" ::: "memory"); }
    __syncthreads();
    COMPUTE0((tt & 1) * 4096);
    __syncthreads();
    if (tt < 6) STAGE0(tt + 2, (tt & 1) * 4096);
  }
#undef STAGE0
#undef COMPUTE0

  // ---- LDS-transposed epilogue: E[col 128][16 granules x 8ch], XOR-swizzled ----
  unsigned short* E = SH;   // 32768 B, exactly fits
#pragma unroll
  for (int i = 0; i < 2; i++) {
    int ob = m0 + wr * 32 + i * 16 + g * 4;
    float bs0 = bias[ob + 0], bs1 = bias[ob + 1], bs2 = bias[ob + 2], bs3 = bias[ob + 3];
    float sc = (ob >= 256 && ob < 512) ? KSC : 1.0f;
    int lobg = wr * 4 + i * 2 + (g >> 1);
#pragma unroll
    for (int j = 0; j < 4; j++) {
      int lc = wc * 64 + j * 16 + q;
      ushort4 o;
      o.x = f2bf((acc[i][j][0] + bs0) * sc);
      o.y = f2bf((acc[i][j][1] + bs1) * sc);
      o.z = f2bf((acc[i][j][2] + bs2) * sc);
      o.w = f2bf((acc[i][j][3] + bs3) * sc);
      *(ushort4*)&E[lc * 128 + ((lobg ^ (lc & 7)) << 3) + (g & 1) * 4] = o;
    }
  }
  __syncthreads();
  int c = t >> 2, part = t & 3;
  int col = n0 + c;
  if (col < N) {
    int mt = m0 >> 7;            // 0..5
    unsigned short* dst;
    if (mt < 4) {                // q,k head-panels
      int hd = (mt & 1) * 4 + part;
      int sl = (mt >> 1) * 8 + hd;           // isK*8 + head
      int p_ord = (hd >= 4) ? ((col % Wn) * Wn + col / Wn) : col;
      dst = qkh + (((size_t)b * 16 + sl) * HWn + p_ord) * 32;
    } else {                     // v pixel-major
      dst = outV + ((size_t)b * HWn + col) * 256 + (m0 - 512) + part * 32;
    }
#pragma unroll
    for (int k2 = part * 4; k2 < part * 4 + 4; k2++) {   // 32 chans = 64B contiguous
      short8 v = *(const short8*)&E[c * 128 + ((k2 ^ (c & 7)) << 3)];
      *(short8*)(dst + (k2 - part * 4) * 8) = v;
    }
  }
}

// ---------------- proj GEMM (M=256, K=256, BK=64) ----------------
__global__ __launch_bounds__(512) void k_gemm1(const unsigned short* __restrict__ A,
                                               const unsigned short* __restrict__ Bt,
                                               const float* __restrict__ bias,
                                               float* __restrict__ outF,
                                               int M, int N, int nm, int nper) {
  const int K = 256;
  __shared__ __align__(16) char SH[67584];
  unsigned short* As = (unsigned short*)SH;   // [2][8192]
  unsigned short* Bs = As + 16384;            // [2][8192]
  int t = threadIdx.x;
  int raw = blockIdx.x;
  int chunk = gridDim.x >> 3;
  int wg = (raw & 7) * chunk + (raw >> 3);
  int b = wg / nper, r = wg % nper;
  int m0 = (r % nm) * 128, n0 = (r / nm) * 128;
  const unsigned short* Bb = Bt + (size_t)b * N * K;
  int lane = t & 63, w = t >> 6;
  int wr = w >> 1, wc = w & 1;
  int g = lane >> 4, q = lane & 15;
  int srow8 = lane >> 3;
  int slot = lane & 7;

  const unsigned short* Ag[2];
  const unsigned short* Bg[2];
  int ldst[2];
#pragma unroll
  for (int i = 0; i < 2; i++) {
    int row = i * 64 + w * 8 + srow8;
    int cs = slot ^ srow8;
    Ag[i] = A + (size_t)(m0 + row) * K + cs * 8;
    int nr = n0 + row;
    Bg[i] = Bb + (size_t)((nr < N) ? nr : (N - 1)) * K + cs * 8;
    ldst[i] = (i * 64 + w * 8) * 64;
  }

  floatx4 z4 = {0.f, 0.f, 0.f, 0.f};
  floatx4 acc[2][4];
#pragma unroll
  for (int i = 0; i < 2; i++)
#pragma unroll
    for (int j = 0; j < 4; j++) acc[i][j] = z4;

#define STAGE(kt, off) do {                                                    \
    _Pragma("unroll")                                                          \
    for (int i = 0; i < 2; i++) gload16(Ag[i] + (kt) * 64, &As[(off) + ldst[i]]); \
    _Pragma("unroll")                                                          \
    for (int i = 0; i < 2; i++) gload16(Bg[i] + (kt) * 64, &Bs[(off) + ldst[i]]); \
  } while (0)

#define COMPUTE(off) do {                                                      \
    _Pragma("unroll")                                                          \
    for (int kk = 0; kk < 64; kk += 32) {                                      \
      short8 af[2], bfr[4];                                                    \
      _Pragma("unroll")                                                        \
      for (int i = 0; i < 2; i++) {                                            \
        int row = wr * 32 + i * 16 + q;                                        \
        af[i] = *(const short8*)&As[(off) + row * 64 + ((((kk >> 3) + g) ^ (q & 7)) << 3)]; \
      }                                                                        \
      _Pragma("unroll")                                                        \
      for (int j = 0; j < 4; j++) {                                            \
        int row = wc * 64 + j * 16 + q;                                        \
        bfr[j] = *(const short8*)&Bs[(off) + row * 64 + ((((kk >> 3) + g) ^ (q & 7)) << 3)]; \
      }                                                                        \
      _Pragma("unroll")                                                        \
      for (int i = 0; i < 2; i++)                                              \
        _Pragma("unroll")                                                      \
        for (int j = 0; j < 4; j++)                                            \
          acc[i][j] = __builtin_amdgcn_mfma_f32_16x16x32_bf16(af[i], bfr[j], acc[i][j], 0, 0, 0); \
    }                                                                          \
  } while (0)

  STAGE(0, 0);
  STAGE(1, 8192);
  asm volatile("s_waitcnt vmcnt(4)" ::: "memory");
  __syncthreads();
  COMPUTE(0);
  __syncthreads();
  STAGE(2, 0);
  asm volatile("s_waitcnt vmcnt(4)" ::: "memory");
  __syncthreads();
  COMPUTE(8192);
  __syncthreads();
  STAGE(3, 8192);
  asm volatile("s_waitcnt vmcnt(4)" ::: "memory");
  __syncthreads();
  COMPUTE(0);
  asm volatile("s_waitcnt vmcnt(0)" ::: "memory");
  __syncthreads();
  COMPUTE(8192);
#undef STAGE
#undef COMPUTE

  __syncthreads();
  float* Ef = (float*)SH;   // [row 128][132]
#pragma unroll
  for (int i = 0; i < 2; i++) {
    int ob = m0 + wr * 32 + i * 16 + g * 4;
    int lob = wr * 32 + i * 16 + g * 4;
    float bs0 = bias[ob + 0], bs1 = bias[ob + 1], bs2 = bias[ob + 2], bs3 = bias[ob + 3];
#pragma unroll
    for (int j = 0; j < 4; j++) {
      int lc = wc * 64 + j * 16 + q;
      Ef[(lob + 0) * 132 + lc] = acc[i][j][0] + bs0;
      Ef[(lob + 1) * 132 + lc] = acc[i][j][1] + bs1;
      Ef[(lob + 2) * 132 + lc] = acc[i][j][2] + bs2;
      Ef[(lob + 3) * 132 + lc] = acc[i][j][3] + bs3;
    }
  }
  __syncthreads();
  int rr = t >> 2, seg = t & 3;
  float* dst = outF + (size_t)b * M * N + (size_t)(m0 + rr) * N + n0;
#pragma unroll
  for (int k2 = 0; k2 < 8; k2++) {
    int col = seg * 32 + k2 * 4;
    if (n0 + col < N) {
      floatx4 v = *(const floatx4*)&Ef[rr * 132 + col];
      *(floatx4*)(dst + col) = v;
    }
  }
}

// ---------------- depthwise 3x3 on v (vb[b][px][256]), output vmt[b][ch][pixel] ----------------
__global__ __launch_bounds__(512) void k_dwconv_t(const unsigned short* __restrict__ vb,
                                                  const float* __restrict__ wdw,
                                                  const float* __restrict__ bdw,
                                                  unsigned short* __restrict__ vmt) {
  __shared__ float wS[1152];
  __shared__ float bS[128];
  __shared__ __align__(16) unsigned short tile[32][140];
  int t = threadIdx.x;
  int pass = blockIdx.y, b = blockIdx.z;
  for (int i = t; i < 1152; i += 512) wS[i] = wdw[pass * 1152 + i];
  if (t < 128) bS[t] = bdw[pass * 128 + t];
  __syncthreads();

  int pi = t >> 4, c8 = (t & 15) * 8;
  int i32 = blockIdx.x * 32 + pi;
  int h, w;
  if (pass == 0) { h = i32 / Wn; w = i32 % Wn; }
  else           { w = i32 / Hn; h = i32 % Hn; }

  const unsigned short* vq = vb + pass * 128 + c8;
  float a[8];
  short8 vc = *(const short8*)(vq + ((size_t)b * HWn + h * Wn + w) * 256);
#pragma unroll
  for (int e = 0; e < 8; e++) a[e] = bf2f((unsigned short)vc[e]) + bS[c8 + e];
#pragma unroll
  for (int ky = 0; ky < 3; ky++) {
    int hh = h + ky - 1;
    if (hh < 0 || hh >= Hn) continue;
#pragma unroll
    for (int kx = 0; kx < 3; kx++) {
      int ww = w + kx - 1;
      if (ww < 0 || ww >= Wn) continue;
      short8 vn = *(const short8*)(vq + ((size_t)b * HWn + hh * Wn + ww) * 256);
#pragma unroll
      for (int e = 0; e < 8; e++) a[e] += bf2f((unsigned short)vn[e]) * wS[(c8 + e) * 9 + ky * 3 + kx];
    }
  }
  short8 o;
#pragma unroll
  for (int e = 0; e < 8; e++) o[e] = (short)f2bf(a[e]);
  *(short8*)&tile[pi][c8] = o;
  __syncthreads();

  int dd = t >> 2, quarter = t & 3;
  short8 ov;
#pragma unroll
  for (int k2 = 0; k2 < 8; k2++) ov[k2] = (short)tile[quarter * 8 + k2][dd];
  *(short8*)(vmt + ((size_t)(b * Cn + pass * 128 + dd)) * HWn + blockIdx.x * 32 + quarter * 8) = ov;
}

// ---------------- stripe attention (two-phase scores: peak 52 score VGPRs) ----------------
// grid: (stripe 0..7, b*8+hd 0..63), 512 threads (8 waves)
__global__ __launch_bounds__(512) void k_attn(const unsigned short* __restrict__ qkh,
                                              const unsigned short* __restrict__ vmt,
                                              unsigned short* __restrict__ aout) {
  __shared__ __align__(16) unsigned short Ks[12288];  // 24 j * 4 g * 16 q granules
  __shared__ __align__(16) unsigned short Vf[12800];  // 50 Gc * 32 d granules (d swizzled)
  __shared__ __align__(16) unsigned short Pf[4096];   // 8 waves * 4 Gl * 16 q granules
  int s = blockIdx.x;
  int hd = blockIdx.y & 7, b = blockIdx.y >> 3;
  int t = threadIdx.x, lane = t & 63, wv = t >> 6;
  bool wst = (hd >= 4);
  int q = lane & 15, g = lane >> 4;
  int sbase = s * SEQ;

  const unsigned short* qh = qkh + (((size_t)b * 16 + hd) * HWn + sbase) * 32;
  const unsigned short* kh = qkh + (((size_t)b * 16 + 8 + hd) * HWn + sbase) * 32;

  // ---- Q prefetch ----
  short8 qpre[4];
#pragma unroll
  for (int it = 0; it < 4; it++) {
    int qb = it * 8 + wv;
    int qi = qb * 16 + q;
    int qil = (qi < SEQ) ? qi : 391;
    qpre[it] = *(const short8*)(qh + (size_t)qil * 32 + g * 8);
  }

  // ---- stage K keys 0..383, fragment-major ----
#pragma unroll
  for (int P = 0; P < 3; P++) {
    int key = P * 128 + (t >> 2);
    int gg = t & 3;
    short8 kv = *(const short8*)(kh + (size_t)key * 32 + gg * 8);
    *(short8*)&Ks[((((key >> 4) * 4 + gg) * 16) + (key & 15)) * 8] = kv;
  }
  short8 kf24;
  {
    int key = 384 + q; if (key > 391) key = 391;
    kf24 = *(const short8*)(kh + (size_t)key * 32 + g * 8);
  }
  // ---- stage V fragment-major with d-swizzle ----
  const unsigned short* vg = vmt + ((size_t)(b * Cn + hd * HDIM)) * HWn + sbase;
  for (int idx = t; idx < 1600; idx += 512) {
    int d = idx / 50, Gc = idx % 50;
    short8 vv = *(const short8*)(vg + (size_t)d * HWn + Gc * 8);
    *(short8*)&Vf[(Gc * 32 + (d ^ (Gc & 7))) * 8] = vv;
  }
  __syncthreads();

  floatx4 z4 = {0.f, 0.f, 0.f, 0.f};
  unsigned short* Pw = &Pf[wv * 512];
  int gh = g >> 1, ge = (g & 1) * 4;

#pragma unroll
  for (int it = 0; it < 4; it++) {
    int qb = it * 8 + wv;
    if (qb >= 25) continue;
    int qi = qb * 16 + q;
    int qil = (qi < SEQ) ? qi : 391;
    short8 qf = qpre[it];

    floatx4 sph[13];
    float sm = 0.f;
    floatx4 o0 = z4, o1 = z4;

// write P chunk for sacc pair (arrA, idxA valid; arrB may be the zero tail)
#define WRITEPX(sA_, sB_, validB) do {                                         \
    uint2 wA, wB;                                                              \
    wA.x = cvt_pk_bf16((sA_)[0], (sA_)[1]);                                    \
    wA.y = cvt_pk_bf16((sA_)[2], (sA_)[3]);                                    \
    if (validB) {                                                              \
      wB.x = cvt_pk_bf16((sB_)[0], (sB_)[1]);                                  \
      wB.y = cvt_pk_bf16((sB_)[2], (sB_)[3]);                                  \
    } else { wB.x = 0u; wB.y = 0u; }                                           \
    *(uint2*)&Pw[(gh * 16 + q) * 8 + ge] = wA;                                 \
    *(uint2*)&Pw[((2 + gh) * 16 + q) * 8 + ge] = wB;                           \
  } while (0)

#define PVSTEP(ch) do {                                                        \
    asm volatile("s_waitcnt lgkmcnt(0)" ::: "memory");                         \
    short8 pfr = *(const short8*)&Pw[(g * 16 + q) * 8];                        \
    int Gc = (ch) * 4 + g; if (Gc > 49) Gc = 49;                               \
    int sw = Gc & 7;                                                           \
    short8 vf0 = *(const short8*)&Vf[(Gc * 32 + (q ^ sw)) * 8];                \
    short8 vf1 = *(const short8*)&Vf[(Gc * 32 + 16 + (q ^ sw)) * 8];           \
    pfr_ = pfr; vf0_ = vf0; vf1_ = vf1;                                        \
  } while (0)

    short8 pfr_, vf0_, vf1_;

    // ======== phase A: j 0..11 (chunks 0..5) ========
    __builtin_amdgcn_s_setprio(1);
#pragma unroll
    for (int j = 0; j < 12; j++) {
      short8 kf = *(const short8*)&Ks[((j * 4 + g) * 16 + q) * 8];
      sph[j] = __builtin_amdgcn_mfma_f32_16x16x32_bf16(kf, qf, z4, 0, 0, 0);
    }
    __builtin_amdgcn_s_setprio(0);
#pragma unroll
    for (int j = 0; j < 12; j++) {
      float e0 = EXP2(sph[j][0]); float e1 = EXP2(sph[j][1]);
      float e2 = EXP2(sph[j][2]); float e3 = EXP2(sph[j][3]);
      sph[j][0] = e0; sph[j][1] = e1; sph[j][2] = e2; sph[j][3] = e3;
      sm += (e0 + e1) + (e2 + e3);
    }
    WRITEPX(sph[0], sph[1], true);
#pragma unroll
    for (int ch = 0; ch < 6; ch++) {
      PVSTEP(ch);
      if (ch < 5) {
        switch (ch + 1) {
          case 1: WRITEPX(sph[2], sph[3], true); break;
          case 2: WRITEPX(sph[4], sph[5], true); break;
          case 3: WRITEPX(sph[6], sph[7], true); break;
          case 4: WRITEPX(sph[8], sph[9], true); break;
          case 5: WRITEPX(sph[10], sph[11], true); break;
        }
      }
      __builtin_amdgcn_s_setprio(1);
      o0 = __builtin_amdgcn_mfma_f32_16x16x32_bf16(vf0_, pfr_, o0, 0, 0, 0);
      o1 = __builtin_amdgcn_mfma_f32_16x16x32_bf16(vf1_, pfr_, o1, 0, 0, 0);
      __builtin_amdgcn_s_setprio(0);
    }

    // ======== phase B: j 12..24 (chunks 6..12) ========
    __builtin_amdgcn_s_setprio(1);
#pragma unroll
    for (int j = 0; j < 12; j++) {
      short8 kf = *(const short8*)&Ks[(((j + 12) * 4 + g) * 16 + q) * 8];
      sph[j] = __builtin_amdgcn_mfma_f32_16x16x32_bf16(kf, qf, z4, 0, 0, 0);
    }
    sph[12] = __builtin_amdgcn_mfma_f32_16x16x32_bf16(kf24, qf, z4, 0, 0, 0);
    __builtin_amdgcn_s_setprio(0);
    if (g >= 2) { sph[12][0] = sph[12][1] = sph[12][2] = sph[12][3] = -3.0e38f; }
#pragma unroll
    for (int j = 0; j < 13; j++) {
      float e0 = EXP2(sph[j][0]); float e1 = EXP2(sph[j][1]);
      float e2 = EXP2(sph[j][2]); float e3 = EXP2(sph[j][3]);
      sph[j][0] = e0; sph[j][1] = e1; sph[j][2] = e2; sph[j][3] = e3;
      sm += (e0 + e1) + (e2 + e3);
    }
    WRITEPX(sph[0], sph[1], true);
#pragma unroll
    for (int ch = 6; ch < 13; ch++) {
      PVSTEP(ch);
      if (ch < 12) {
        switch (ch + 1) {
          case 7:  WRITEPX(sph[2], sph[3], true); break;
          case 8:  WRITEPX(sph[4], sph[5], true); break;
          case 9:  WRITEPX(sph[6], sph[7], true); break;
          case 10: WRITEPX(sph[8], sph[9], true); break;
          case 11: WRITEPX(sph[10], sph[11], true); break;
          case 12: WRITEPX(sph[12], sph[12], false); break;
        }
      }
      __builtin_amdgcn_s_setprio(1);
      o0 = __builtin_amdgcn_mfma_f32_16x16x32_bf16(vf0_, pfr_, o0, 0, 0, 0);
      o1 = __builtin_amdgcn_mfma_f32_16x16x32_bf16(vf1_, pfr_, o1, 0, 0, 0);
      __builtin_amdgcn_s_setprio(0);
    }
#undef WRITEPX
#undef PVSTEP

    sm += __shfl_xor(sm, 16);
    sm += __shfl_xor(sm, 32);
    float rcp = 1.0f / sm;

    if (qi < SEQ) {
      int pq = wst ? ((qil % Wn) * Wn + s * 7 + qil / Wn) : (sbase + qil);
      size_t ob = ((size_t)b * HWn + pq) * Cn + hd * HDIM;
      ushort4 u0, u1;
      u0.x = f2bf(o0[0] * rcp); u0.y = f2bf(o0[1] * rcp);
      u0.z = f2bf(o0[2] * rcp); u0.w = f2bf(o0[3] * rcp);
      u1.x = f2bf(o1[0] * rcp); u1.y = f2bf(o1[1] * rcp);
      u1.z = f2bf(o1[2] * rcp); u1.w = f2bf(o1[3] * rcp);
      *(ushort4*)(aout + ob + g * 4) = u0;
      *(ushort4*)(aout + ob + 16 + g * 4) = u1;
    }
  }
}

extern "C" void kernel_launch(void* const* d_in, const int* in_sizes, int n_in,
                              void* d_out, int out_size, void* d_ws, size_t ws_size,
                              hipStream_t stream) {
  const float* x     = (const float*)d_in[0];
  const float* wqkv  = (const float*)d_in[1];
  const float* bqkv  = (const float*)d_in[2];
  const float* wdw   = (const float*)d_in[3];
  const float* bdw   = (const float*)d_in[4];
  const float* wproj = (const float*)d_in[5];
  const float* bproj = (const float*)d_in[6];
  float* out = (float*)d_out;

  unsigned short* xt   = (unsigned short*)d_ws;                    // [B][HW][256] bf16
  unsigned short* wqb  = xt + (size_t)Bn * HWn * Cn;               // [768][256]
  unsigned short* wpb  = wqb + 768 * 256;                          // [256][256]
  unsigned short* qkh  = wpb + 256 * 256;                          // [B][16][HW][32] head-panels
  unsigned short* vb   = qkh + (size_t)Bn * 16 * HWn * 32;         // [B][HW][256] v pixel-major
  unsigned short* vmt  = vb + (size_t)Bn * HWn * Cn;               // [B][256ch][HW]
  unsigned short* aout = vmt + (size_t)Bn * HWn * Cn;              // [B][HW][256]

  k_prep<<<dim3(256 + 98 * 8 * Bn), 256, 0, stream>>>(wqkv, wproj, wqb, wpb, x, xt);
  k_gemm0<<<dim3(1200), 512, 0, stream>>>(wqb, xt, bqkv, qkh, vb);
  k_dwconv_t<<<dim3(98, 2, Bn), 512, 0, stream>>>(vb, wdw, bdw, vmt);
  k_attn<<<dim3(NSTR, Bn * NHEADS), 512, 0, stream>>>(qkh, vmt, aout);
  k_gemm1<<<dim3(400), 512, 0, stream>>>(wpb, aout, bproj, out, 256, HWn, 2, 50);
}